// Round 1
// baseline (1375.111 us; speedup 1.0000x reference)
//
#include <hip/hip_runtime.h>
#include <cstdint>
#include <cstddef>

#define NN 50000            // nodes
#define NE 800000           // edges (before self loops)
#define NT (NE + NN)        // edges incl self loops
#define NG 64               // graphs
#define BN_EPS 1e-5f

// ---------------------------------------------------------------------------
// int64-vs-int32 detection for edge_index / batch (harness doc says int32,
// reference says int64; detect on device, branch uniformly).
// int64 little-endian values < 2^31 => odd 32-bit words are all zero.
__global__ void k_detect(const int* __restrict__ ei, int* __restrict__ flag) {
    if (blockIdx.x == 0 && threadIdx.x == 0) {
        int is64 = (ei[1] == 0 && ei[3] == 0 && ei[5] == 0 && ei[7] == 0) ? 1 : 0;
        *flag = is64;
    }
}

__device__ __forceinline__ int ld_idx(const int* __restrict__ p, long i, int is64) {
    return is64 ? p[2 * i] : p[i];
}

// ---------------------------------------------------------------------------
// weighted in-degree + edge count per dst (includes self loops, w=1)
__global__ void k_deg_count(const int* __restrict__ ei, const float* __restrict__ ew,
                            const int* __restrict__ flag,
                            float* __restrict__ deg, int* __restrict__ cnt) {
    const int is64 = *flag;
    int i = blockIdx.x * 256 + threadIdx.x;
    const int stride = gridDim.x * 256;
    for (; i < NT; i += stride) {
        int d; float w;
        if (i < NE) { d = ld_idx(ei, (long)NE + i, is64); w = ew[i]; }
        else        { d = i - NE;                          w = 1.0f;  }
        atomicAdd(&deg[d], w);
        atomicAdd(&cnt[d], 1);
    }
}

// exclusive prefix sum of cnt -> rowptr (and cursor copy). single block.
__global__ void k_scan(const int* __restrict__ cnt, int* __restrict__ rowptr,
                       int* __restrict__ cursor) {
    __shared__ int warp_excl[16];
    __shared__ int s_base;
    __shared__ int s_chunk_total;
    const int tid  = threadIdx.x;
    const int lane = tid & 63;
    const int wid  = tid >> 6;
    if (tid == 0) s_base = 0;
    __syncthreads();
    for (int start = 0; start < NN; start += 1024) {
        const int idx = start + tid;
        const int v = (idx < NN) ? cnt[idx] : 0;
        // inclusive wave scan
        int s = v;
        #pragma unroll
        for (int off = 1; off < 64; off <<= 1) {
            int t = __shfl_up(s, off, 64);
            if (lane >= off) s += t;
        }
        if (lane == 63) warp_excl[wid] = s;
        __syncthreads();
        if (tid == 0) {
            int acc = 0;
            #pragma unroll
            for (int w = 0; w < 16; ++w) { int t = warp_excl[w]; warp_excl[w] = acc; acc += t; }
        }
        __syncthreads();
        const int incl = s + warp_excl[wid];
        if (tid == 1023) s_chunk_total = incl;
        const int excl = incl - v;
        if (idx < NN) { const int r = s_base + excl; rowptr[idx] = r; cursor[idx] = r; }
        __syncthreads();
        if (tid == 0) s_base += s_chunk_total;
        __syncthreads();
    }
    if (tid == 0) rowptr[NN] = s_base;
}

__global__ void k_dis(const float* __restrict__ deg, float* __restrict__ dis) {
    const int i = blockIdx.x * 256 + threadIdx.x;
    if (i < NN) dis[i] = deg[i] > 0.0f ? rsqrtf(deg[i]) : 0.0f;
}

// scatter edges into CSR (by dst), value = dis[src]*w*dis[dst]
__global__ void k_csr(const int* __restrict__ ei, const float* __restrict__ ew,
                      const int* __restrict__ flag, const float* __restrict__ dis,
                      int* __restrict__ cursor, int* __restrict__ col,
                      float* __restrict__ val) {
    const int is64 = *flag;
    int i = blockIdx.x * 256 + threadIdx.x;
    const int stride = gridDim.x * 256;
    for (; i < NT; i += stride) {
        int s, d; float w;
        if (i < NE) { s = ld_idx(ei, i, is64); d = ld_idx(ei, (long)NE + i, is64); w = ew[i]; }
        else        { s = d = i - NE;          w = 1.0f;  }
        const int pos = atomicAdd(&cursor[d], 1);
        col[pos] = s;
        val[pos] = dis[s] * w * dis[d];
    }
}

// ---------------------------------------------------------------------------
// SpMM: out[v][f] = sum_{e in row v} val[e] * x[col[e]][f]   (F = 32/64/128)
template <int F>
__global__ void k_spmm(const int* __restrict__ rowptr, const int* __restrict__ col,
                       const float* __restrict__ val, const float* __restrict__ x,
                       float* __restrict__ out) {
    constexpr int NPB = 256 / F;
    const int node = blockIdx.x * NPB + threadIdx.x / F;
    const int f = threadIdx.x % F;
    if (node >= NN) return;
    const int beg = rowptr[node], end = rowptr[node + 1];
    float acc = 0.0f;
    for (int e = beg; e < end; ++e) {
        const int s = col[e];
        const float v = val[e];
        acc += x[(long)s * F + f] * v;
    }
    out[(long)node * F + f] = acc;
}

// ---------------------------------------------------------------------------
// fp32 tiled GEMM: C[M,Nc] = A[M,K] @ B[K,Nc]; 64x64 tile, 4x4 per thread
__global__ void k_gemm(const float* __restrict__ A, const float* __restrict__ B,
                       float* __restrict__ C, int M, int K, int Nc) {
    __shared__ float sA[16][64];
    __shared__ float sB[16][64];
    const int tx = threadIdx.x % 16;   // n
    const int ty = threadIdx.x / 16;   // m
    const int m0 = blockIdx.x * 64;
    const int n0 = blockIdx.y * 64;
    float acc[4][4] = {};
    for (int kt = 0; kt < K; kt += 16) {
        #pragma unroll
        for (int l = 0; l < 4; ++l) {
            const int idx = threadIdx.x + l * 256;
            const int r = idx / 16, kk = idx % 16;
            const int gm = m0 + r;
            sA[kk][r] = (gm < M) ? A[(long)gm * K + kt + kk] : 0.0f;
        }
        #pragma unroll
        for (int l = 0; l < 4; ++l) {
            const int idx = threadIdx.x + l * 256;
            const int kk = idx / 64, c = idx % 64;
            const int gn = n0 + c;
            sB[kk][c] = (gn < Nc) ? B[(long)(kt + kk) * Nc + gn] : 0.0f;
        }
        __syncthreads();
        #pragma unroll
        for (int kk = 0; kk < 16; ++kk) {
            float a[4], b[4];
            #pragma unroll
            for (int i = 0; i < 4; ++i) a[i] = sA[kk][ty * 4 + i];
            #pragma unroll
            for (int j = 0; j < 4; ++j) b[j] = sB[kk][tx * 4 + j];
            #pragma unroll
            for (int i = 0; i < 4; ++i)
                #pragma unroll
                for (int j = 0; j < 4; ++j) acc[i][j] += a[i] * b[j];
        }
        __syncthreads();
    }
    #pragma unroll
    for (int i = 0; i < 4; ++i) {
        const int gm = m0 + ty * 4 + i;
        if (gm >= M) continue;
        #pragma unroll
        for (int j = 0; j < 4; ++j) {
            const int gn = n0 + tx * 4 + j;
            if (gn < Nc) C[(long)gm * Nc + gn] = acc[i][j];
        }
    }
}

// ---------------------------------------------------------------------------
// BN stats: per-column sum & sumsq via per-block partials + atomics
__global__ void k_bn_stats(const float* __restrict__ x, float* __restrict__ stats, int F) {
    const int f = threadIdx.x;
    const long r0 = (long)blockIdx.x * 64;
    const long r1 = (r0 + 64 < NN) ? r0 + 64 : NN;
    float s = 0.0f, ss = 0.0f;
    for (long r = r0; r < r1; ++r) {
        const float v = x[r * F + f];
        s += v; ss += v * v;
    }
    atomicAdd(&stats[f], s);
    atomicAdd(&stats[F + f], ss);
}

__global__ void k_bn_final(const float* __restrict__ stats, const float* __restrict__ g,
                           const float* __restrict__ be, float* __restrict__ ac, int F) {
    const int f = threadIdx.x;
    const float mu  = stats[f] * (1.0f / NN);
    const float var = stats[F + f] * (1.0f / NN) - mu * mu;
    const float a = g[f] * rsqrtf(var + BN_EPS);
    ac[f]     = a;
    ac[F + f] = be[f] - mu * a;
}

__global__ void k_bn_apply(float* __restrict__ x, const float* __restrict__ ac, int F) {
    const long i = (long)blockIdx.x * 256 + threadIdx.x;
    if (i >= (long)NN * F) return;
    const int f = (int)(i & (F - 1));            // F is a power of two
    const float v = x[i] * ac[f] + ac[F + f];
    x[i] = v > 0.0f ? v : 0.0f;
}

// ---------------------------------------------------------------------------
// pooling: per-graph sums + counts (batch is sorted but atomics are fine here)
__global__ void k_pool(const float* __restrict__ h, const int* __restrict__ batch,
                       const int* __restrict__ flag,
                       float* __restrict__ psum, float* __restrict__ pcnt) {
    const int is64 = *flag;
    const int node = blockIdx.x * 8 + threadIdx.x / 32;
    const int f = threadIdx.x & 31;
    if (node >= NN) return;
    const int g = ld_idx(batch, node, is64);
    atomicAdd(&psum[g * 32 + f], h[(long)node * 32 + f]);
    if (f == 0) atomicAdd(&pcnt[g], 1.0f);
}

__global__ void k_head(const float* __restrict__ psum, const float* __restrict__ pcnt,
                       const float* __restrict__ Wl, const float* __restrict__ bl,
                       float* __restrict__ out) {
    const int g = threadIdx.x;
    if (g >= NG) return;
    float c = pcnt[g]; c = c > 1.0f ? c : 1.0f;
    float acc = 0.0f;
    #pragma unroll
    for (int f = 0; f < 32; ++f) acc += (psum[g * 32 + f] / c) * Wl[f];
    acc += bl[0];
    out[g] = 1.0f / (1.0f + expf(-acc));
}

// ---------------------------------------------------------------------------
extern "C" void kernel_launch(void* const* d_in, const int* in_sizes, int n_in,
                              void* d_out, int out_size, void* d_ws, size_t ws_size,
                              hipStream_t stream) {
    const float* x     = (const float*)d_in[0];
    const int*   ei    = (const int*)d_in[1];
    const float* ew    = (const float*)d_in[2];
    const int*   batch = (const int*)d_in[3];
    const float* W1 = (const float*)d_in[4];
    const float* g1 = (const float*)d_in[6];
    const float* be1 = (const float*)d_in[7];
    const float* W2 = (const float*)d_in[8];
    const float* g2 = (const float*)d_in[10];
    const float* be2 = (const float*)d_in[11];
    const float* W3 = (const float*)d_in[12];
    const float* g3 = (const float*)d_in[14];
    const float* be3 = (const float*)d_in[15];
    const float* W4 = (const float*)d_in[16];
    const float* g4 = (const float*)d_in[18];
    const float* be4 = (const float*)d_in[19];
    const float* Wl = (const float*)d_in[20];
    const float* bl = (const float*)d_in[21];
    float* out = (float*)d_out;

    char* ws = (char*)d_ws;
    size_t off = 0;
    auto alloc = [&](size_t bytes) -> void* {
        void* p = ws + off;
        off += (bytes + 255) & ~(size_t)255;
        return p;
    };
    // zeroed region first (one memset)
    float* deg   = (float*)alloc((size_t)NN * 4);
    int*   cnt   = (int*)  alloc((size_t)NN * 4);
    float* psum  = (float*)alloc((size_t)NG * 32 * 4);
    float* pcnt  = (float*)alloc((size_t)NG * 4);
    float* stats = (float*)alloc(4 * 512 * 4);     // 4 layers x (sum,sumsq) x <=256
    const size_t zero_bytes = off;
    // non-zeroed
    int*   flag   = (int*)  alloc(256);
    float* ac     = (float*)alloc(512 * 4);
    int*   rowptr = (int*)  alloc((size_t)(NN + 1) * 4);
    int*   cursor = (int*)  alloc((size_t)NN * 4);
    float* dis    = (float*)alloc((size_t)NN * 4);
    int*   col    = (int*)  alloc((size_t)NT * 4);
    float* val    = (float*)alloc((size_t)NT * 4);
    float* bufA   = (float*)alloc((size_t)NN * 256 * 4);
    float* bufB   = (float*)alloc((size_t)NN * 256 * 4);

    hipMemsetAsync(d_ws, 0, zero_bytes, stream);

    const int egrid = (NT + 255) / 256;

    k_detect<<<1, 64, 0, stream>>>(ei, flag);
    k_deg_count<<<egrid, 256, 0, stream>>>(ei, ew, flag, deg, cnt);
    k_scan<<<1, 1024, 0, stream>>>(cnt, rowptr, cursor);
    k_dis<<<(NN + 255) / 256, 256, 0, stream>>>(deg, dis);
    k_csr<<<egrid, 256, 0, stream>>>(ei, ew, flag, dis, cursor, col, val);

    // ---- layer 1: aggregate(128) -> GEMM 128x256 -> BN+ReLU(256)
    k_spmm<128><<<NN / 2, 256, 0, stream>>>(rowptr, col, val, x, bufA);
    k_gemm<<<dim3((NN + 63) / 64, 4), 256, 0, stream>>>(bufA, W1, bufB, NN, 128, 256);
    k_bn_stats<<<(NN + 63) / 64, 256, 0, stream>>>(bufB, stats + 0 * 512, 256);
    k_bn_final<<<1, 256, 0, stream>>>(stats + 0 * 512, g1, be1, ac, 256);
    k_bn_apply<<<(int)(((long)NN * 256 + 255) / 256), 256, 0, stream>>>(bufB, ac, 256);

    // ---- layer 2: GEMM 256x128 -> aggregate(128) -> BN+ReLU(128)
    k_gemm<<<dim3((NN + 63) / 64, 2), 256, 0, stream>>>(bufB, W2, bufA, NN, 256, 128);
    k_spmm<128><<<NN / 2, 256, 0, stream>>>(rowptr, col, val, bufA, bufB);
    k_bn_stats<<<(NN + 63) / 64, 128, 0, stream>>>(bufB, stats + 1 * 512, 128);
    k_bn_final<<<1, 128, 0, stream>>>(stats + 1 * 512, g2, be2, ac, 128);
    k_bn_apply<<<(int)(((long)NN * 128 + 255) / 256), 256, 0, stream>>>(bufB, ac, 128);

    // ---- layer 3: GEMM 128x64 -> aggregate(64) -> BN+ReLU(64)
    k_gemm<<<dim3((NN + 63) / 64, 1), 256, 0, stream>>>(bufB, W3, bufA, NN, 128, 64);
    k_spmm<64><<<NN / 4, 256, 0, stream>>>(rowptr, col, val, bufA, bufB);
    k_bn_stats<<<(NN + 63) / 64, 64, 0, stream>>>(bufB, stats + 2 * 512, 64);
    k_bn_final<<<1, 64, 0, stream>>>(stats + 2 * 512, g3, be3, ac, 64);
    k_bn_apply<<<(int)(((long)NN * 64 + 255) / 256), 256, 0, stream>>>(bufB, ac, 64);

    // ---- layer 4: GEMM 64x32 -> aggregate(32) -> BN+ReLU(32)
    k_gemm<<<dim3((NN + 63) / 64, 1), 256, 0, stream>>>(bufB, W4, bufA, NN, 64, 32);
    k_spmm<32><<<NN / 8, 256, 0, stream>>>(rowptr, col, val, bufA, bufB);
    k_bn_stats<<<(NN + 63) / 64, 32, 0, stream>>>(bufB, stats + 3 * 512, 32);
    k_bn_final<<<1, 32, 0, stream>>>(stats + 3 * 512, g4, be4, ac, 32);
    k_bn_apply<<<(int)(((long)NN * 32 + 255) / 256), 256, 0, stream>>>(bufB, ac, 32);

    // ---- pool + head
    k_pool<<<NN / 8, 256, 0, stream>>>(bufB, batch, flag, psum, pcnt);
    k_head<<<1, 64, 0, stream>>>(psum, pcnt, Wl, bl, out);
}

// Round 2
// 821.676 us; speedup vs baseline: 1.6735x; 1.6735x over previous
//
#include <hip/hip_runtime.h>
#include <cstdint>
#include <cstddef>

#define NN 50000            // nodes
#define NE 800000           // edges (before self loops)
#define NT (NE + NN)        // edges incl self loops
#define NG 64               // graphs
#define BN_EPS 1e-5f

// ---------------------------------------------------------------------------
// int64-vs-int32 detection for edge_index / batch (harness doc says int32,
// reference says int64; detect on device, branch uniformly).
__global__ void k_detect(const int* __restrict__ ei, int* __restrict__ flag) {
    if (blockIdx.x == 0 && threadIdx.x == 0) {
        int is64 = (ei[1] == 0 && ei[3] == 0 && ei[5] == 0 && ei[7] == 0) ? 1 : 0;
        *flag = is64;
    }
}

__device__ __forceinline__ int ld_idx(const int* __restrict__ p, long i, int is64) {
    return is64 ? p[2 * i] : p[i];
}

// ---------------------------------------------------------------------------
// weighted in-degree + edge count per dst (includes self loops, w=1)
__global__ void k_deg_count(const int* __restrict__ ei, const float* __restrict__ ew,
                            const int* __restrict__ flag,
                            float* __restrict__ deg, int* __restrict__ cnt) {
    const int is64 = *flag;
    int i = blockIdx.x * 256 + threadIdx.x;
    const int stride = gridDim.x * 256;
    for (; i < NT; i += stride) {
        int d; float w;
        if (i < NE) { d = ld_idx(ei, (long)NE + i, is64); w = ew[i]; }
        else        { d = i - NE;                          w = 1.0f;  }
        atomicAdd(&deg[d], w);
        atomicAdd(&cnt[d], 1);
    }
}

// exclusive prefix sum of cnt -> rowptr (and cursor copy). single block.
__global__ void k_scan(const int* __restrict__ cnt, int* __restrict__ rowptr,
                       int* __restrict__ cursor) {
    __shared__ int warp_excl[16];
    __shared__ int s_base;
    __shared__ int s_chunk_total;
    const int tid  = threadIdx.x;
    const int lane = tid & 63;
    const int wid  = tid >> 6;
    if (tid == 0) s_base = 0;
    __syncthreads();
    for (int start = 0; start < NN; start += 1024) {
        const int idx = start + tid;
        const int v = (idx < NN) ? cnt[idx] : 0;
        int s = v;
        #pragma unroll
        for (int off = 1; off < 64; off <<= 1) {
            int t = __shfl_up(s, off, 64);
            if (lane >= off) s += t;
        }
        if (lane == 63) warp_excl[wid] = s;
        __syncthreads();
        if (tid == 0) {
            int acc = 0;
            #pragma unroll
            for (int w = 0; w < 16; ++w) { int t = warp_excl[w]; warp_excl[w] = acc; acc += t; }
        }
        __syncthreads();
        const int incl = s + warp_excl[wid];
        if (tid == 1023) s_chunk_total = incl;
        const int excl = incl - v;
        if (idx < NN) { const int r = s_base + excl; rowptr[idx] = r; cursor[idx] = r; }
        __syncthreads();
        if (tid == 0) s_base += s_chunk_total;
        __syncthreads();
    }
    if (tid == 0) rowptr[NN] = s_base;
}

__global__ void k_dis(const float* __restrict__ deg, float* __restrict__ dis) {
    const int i = blockIdx.x * 256 + threadIdx.x;
    if (i < NN) dis[i] = deg[i] > 0.0f ? rsqrtf(deg[i]) : 0.0f;
}

// scatter edges into CSR (by dst), value = dis[src]*w*dis[dst]
__global__ void k_csr(const int* __restrict__ ei, const float* __restrict__ ew,
                      const int* __restrict__ flag, const float* __restrict__ dis,
                      int* __restrict__ cursor, int* __restrict__ col,
                      float* __restrict__ val) {
    const int is64 = *flag;
    int i = blockIdx.x * 256 + threadIdx.x;
    const int stride = gridDim.x * 256;
    for (; i < NT; i += stride) {
        int s, d; float w;
        if (i < NE) { s = ld_idx(ei, i, is64); d = ld_idx(ei, (long)NE + i, is64); w = ew[i]; }
        else        { s = d = i - NE;          w = 1.0f;  }
        const int pos = atomicAdd(&cursor[d], 1);
        col[pos] = s;
        val[pos] = dis[s] * w * dis[d];
    }
}

// ---------------------------------------------------------------------------
// SpMM, float4 per lane: out[v][f] = sum_e val[e] * x[col[e]][f]
template <int F>
__global__ void k_spmm4(const int* __restrict__ rowptr, const int* __restrict__ col,
                        const float* __restrict__ val, const float* __restrict__ x,
                        float* __restrict__ out) {
    constexpr int L = F / 4;            // lanes per node
    constexpr int NPB = 256 / L;        // nodes per block
    const int node = blockIdx.x * NPB + threadIdx.x / L;
    const int q = threadIdx.x % L;
    if (node >= NN) return;
    const int beg = rowptr[node], end = rowptr[node + 1];
    float4 acc = {0.f, 0.f, 0.f, 0.f};
    for (int e = beg; e < end; ++e) {
        const int s = col[e];
        const float v = val[e];
        const float4 xv = *(const float4*)(x + (long)s * F + q * 4);
        acc.x += v * xv.x; acc.y += v * xv.y; acc.z += v * xv.z; acc.w += v * xv.w;
    }
    *(float4*)(out + (long)node * F + q * 4) = acc;
}

// ---------------------------------------------------------------------------
// fp32 GEMM: C[M,Nc] = A[M,K] @ B[K,Nc]; 128xBN tile, 8xTN per thread,
// 256 threads. sA stored transposed [kk][r] so inner LDS reads are b128
// and bank-conflict-free (ty groups hit banks 0/8/16/24).
template <int BN, int TN>
__global__ void k_gemm2(const float* __restrict__ A, const float* __restrict__ B,
                        float* __restrict__ C, int M, int K, int Nc) {
    __shared__ float sA[16][128];
    __shared__ float sB[16][BN];
    constexpr int TX = BN / TN;              // 16
    const int tx = threadIdx.x % TX;
    const int ty = threadIdx.x / TX;         // 0..15
    const int m0 = blockIdx.x * 128;
    const int n0 = blockIdx.y * BN;
    float acc[8][TN] = {};
    for (int kt = 0; kt < K; kt += 16) {
        #pragma unroll
        for (int l = 0; l < 8; ++l) {
            const int idx = threadIdx.x + l * 256;
            const int r = idx >> 4, kk = idx & 15;
            const int gm = m0 + r;
            sA[kk][r] = (gm < M) ? A[(long)gm * K + kt + kk] : 0.0f;
        }
        #pragma unroll
        for (int l = 0; l < (16 * BN) / 256; ++l) {
            const int idx = threadIdx.x + l * 256;
            const int kk = idx / BN, c = idx % BN;
            sB[kk][c] = B[(long)(kt + kk) * Nc + n0 + c];
        }
        __syncthreads();
        #pragma unroll
        for (int kk = 0; kk < 16; ++kk) {
            float a[8], b[TN];
            #pragma unroll
            for (int i = 0; i < 8; ++i) a[i] = sA[kk][ty * 8 + i];
            #pragma unroll
            for (int j = 0; j < TN; ++j) b[j] = sB[kk][tx * TN + j];
            #pragma unroll
            for (int i = 0; i < 8; ++i)
                #pragma unroll
                for (int j = 0; j < TN; ++j) acc[i][j] += a[i] * b[j];
        }
        __syncthreads();
    }
    #pragma unroll
    for (int i = 0; i < 8; ++i) {
        const int gm = m0 + ty * 8 + i;
        if (gm >= M) continue;
        #pragma unroll
        for (int j = 0; j < TN; ++j) {
            C[(long)gm * Nc + n0 + tx * TN + j] = acc[i][j];
        }
    }
}

// ---------------------------------------------------------------------------
// BN stats: per-column sum & sumsq via per-block partials + atomics
__global__ void k_bn_stats(const float* __restrict__ x, float* __restrict__ stats, int F) {
    const int f = threadIdx.x;
    const long r0 = (long)blockIdx.x * 64;
    const long r1 = (r0 + 64 < NN) ? r0 + 64 : NN;
    float s = 0.0f, ss = 0.0f;
    for (long r = r0; r < r1; ++r) {
        const float v = x[r * F + f];
        s += v; ss += v * v;
    }
    atomicAdd(&stats[f], s);
    atomicAdd(&stats[F + f], ss);
}

__global__ void k_bn_final(const float* __restrict__ stats, const float* __restrict__ g,
                           const float* __restrict__ be, float* __restrict__ ac, int F) {
    const int f = threadIdx.x;
    const float mu  = stats[f] * (1.0f / NN);
    const float var = stats[F + f] * (1.0f / NN) - mu * mu;
    const float a = g[f] * rsqrtf(var + BN_EPS);
    ac[f]     = a;
    ac[F + f] = be[f] - mu * a;
}

__global__ void k_bn_apply(float* __restrict__ x, const float* __restrict__ ac, int F) {
    const long i = (long)blockIdx.x * 256 + threadIdx.x;
    if (i >= (long)NN * F) return;
    const int f = (int)(i & (F - 1));            // F is a power of two
    const float v = x[i] * ac[f] + ac[F + f];
    x[i] = v > 0.0f ? v : 0.0f;
}

// ---------------------------------------------------------------------------
// graph bounds: batch is sorted; gstart[g] = lower_bound(batch, g), g in [0,64]
__global__ void k_bounds(const int* __restrict__ batch, const int* __restrict__ flag,
                         int* __restrict__ gstart) {
    const int g = threadIdx.x;
    if (g > NG) return;
    const int is64 = *flag;
    int lo = 0, hi = NN;
    while (lo < hi) {
        const int mid = (lo + hi) >> 1;
        if (ld_idx(batch, mid, is64) < g) lo = mid + 1; else hi = mid;
    }
    gstart[g] = lo;
}

// fused mean-pool + linear head + sigmoid: one block per graph, no atomics
__global__ void k_pool2(const float* __restrict__ h, const int* __restrict__ gstart,
                        const float* __restrict__ Wl, const float* __restrict__ bl,
                        float* __restrict__ out) {
    const int g = blockIdx.x;
    const int s = gstart[g], e = gstart[g + 1];
    const int f = threadIdx.x & 31, c = threadIdx.x >> 5;   // 8 row-chunks x 32 feats
    float acc = 0.0f;
    for (int r = s + c; r < e; r += 8) acc += h[(long)r * 32 + f];
    __shared__ float red[8][32];
    red[c][f] = acc;
    __syncthreads();
    if (threadIdx.x < 32) {
        float t = 0.0f;
        #pragma unroll
        for (int i = 0; i < 8; ++i) t += red[i][f];
        float cntf = (float)(e - s);
        cntf = cntf > 1.0f ? cntf : 1.0f;
        float p = (t / cntf) * Wl[f];
        #pragma unroll
        for (int off = 16; off > 0; off >>= 1) p += __shfl_down(p, off, 32);
        if (f == 0) out[g] = 1.0f / (1.0f + expf(-(p + bl[0])));
    }
}

// ---------------------------------------------------------------------------
extern "C" void kernel_launch(void* const* d_in, const int* in_sizes, int n_in,
                              void* d_out, int out_size, void* d_ws, size_t ws_size,
                              hipStream_t stream) {
    const float* x     = (const float*)d_in[0];
    const int*   ei    = (const int*)d_in[1];
    const float* ew    = (const float*)d_in[2];
    const int*   batch = (const int*)d_in[3];
    const float* W1 = (const float*)d_in[4];
    const float* g1 = (const float*)d_in[6];
    const float* be1 = (const float*)d_in[7];
    const float* W2 = (const float*)d_in[8];
    const float* g2 = (const float*)d_in[10];
    const float* be2 = (const float*)d_in[11];
    const float* W3 = (const float*)d_in[12];
    const float* g3 = (const float*)d_in[14];
    const float* be3 = (const float*)d_in[15];
    const float* W4 = (const float*)d_in[16];
    const float* g4 = (const float*)d_in[18];
    const float* be4 = (const float*)d_in[19];
    const float* Wl = (const float*)d_in[20];
    const float* bl = (const float*)d_in[21];
    float* out = (float*)d_out;

    char* ws = (char*)d_ws;
    size_t off = 0;
    auto alloc = [&](size_t bytes) -> void* {
        void* p = ws + off;
        off += (bytes + 255) & ~(size_t)255;
        return p;
    };
    // zeroed region first (one memset)
    float* deg   = (float*)alloc((size_t)NN * 4);
    int*   cnt   = (int*)  alloc((size_t)NN * 4);
    float* stats = (float*)alloc(4 * 512 * 4);
    const size_t zero_bytes = off;
    // non-zeroed
    int*   flag   = (int*)  alloc(256);
    float* ac     = (float*)alloc(512 * 4);
    int*   gstart = (int*)  alloc((NG + 1) * 4);
    int*   rowptr = (int*)  alloc((size_t)(NN + 1) * 4);
    int*   cursor = (int*)  alloc((size_t)NN * 4);
    float* dis    = (float*)alloc((size_t)NN * 4);
    int*   col    = (int*)  alloc((size_t)NT * 4);
    float* val    = (float*)alloc((size_t)NT * 4);
    float* bufA   = (float*)alloc((size_t)NN * 256 * 4);
    float* bufB   = (float*)alloc((size_t)NN * 256 * 4);

    hipMemsetAsync(d_ws, 0, zero_bytes, stream);

    const int egrid = (NT + 255) / 256;

    k_detect<<<1, 64, 0, stream>>>(ei, flag);
    k_deg_count<<<egrid, 256, 0, stream>>>(ei, ew, flag, deg, cnt);
    k_scan<<<1, 1024, 0, stream>>>(cnt, rowptr, cursor);
    k_dis<<<(NN + 255) / 256, 256, 0, stream>>>(deg, dis);
    k_csr<<<egrid, 256, 0, stream>>>(ei, ew, flag, dis, cursor, col, val);
    k_bounds<<<1, 128, 0, stream>>>(batch, flag, gstart);

    const int mg = (NN + 127) / 128;   // GEMM grid.x

    // ---- layer 1: aggregate(128) -> GEMM 128x256 -> BN+ReLU(256)
    k_spmm4<128><<<(NN + 7) / 8, 256, 0, stream>>>(rowptr, col, val, x, bufA);
    k_gemm2<64, 4><<<dim3(mg, 4), 256, 0, stream>>>(bufA, W1, bufB, NN, 128, 256);
    k_bn_stats<<<(NN + 63) / 64, 256, 0, stream>>>(bufB, stats + 0 * 512, 256);
    k_bn_final<<<1, 256, 0, stream>>>(stats + 0 * 512, g1, be1, ac, 256);
    k_bn_apply<<<(int)(((long)NN * 256 + 255) / 256), 256, 0, stream>>>(bufB, ac, 256);

    // ---- layer 2: GEMM 256x128 -> aggregate(128) -> BN+ReLU(128)
    k_gemm2<64, 4><<<dim3(mg, 2), 256, 0, stream>>>(bufB, W2, bufA, NN, 256, 128);
    k_spmm4<128><<<(NN + 7) / 8, 256, 0, stream>>>(rowptr, col, val, bufA, bufB);
    k_bn_stats<<<(NN + 63) / 64, 128, 0, stream>>>(bufB, stats + 1 * 512, 128);
    k_bn_final<<<1, 128, 0, stream>>>(stats + 1 * 512, g2, be2, ac, 128);
    k_bn_apply<<<(int)(((long)NN * 128 + 255) / 256), 256, 0, stream>>>(bufB, ac, 128);

    // ---- layer 3: GEMM 128x64 -> aggregate(64) -> BN+ReLU(64)
    k_gemm2<64, 4><<<dim3(mg, 1), 256, 0, stream>>>(bufB, W3, bufA, NN, 128, 64);
    k_spmm4<64><<<(NN + 15) / 16, 256, 0, stream>>>(rowptr, col, val, bufA, bufB);
    k_bn_stats<<<(NN + 63) / 64, 64, 0, stream>>>(bufB, stats + 2 * 512, 64);
    k_bn_final<<<1, 64, 0, stream>>>(stats + 2 * 512, g3, be3, ac, 64);
    k_bn_apply<<<(int)(((long)NN * 64 + 255) / 256), 256, 0, stream>>>(bufB, ac, 64);

    // ---- layer 4: GEMM 64x32 -> aggregate(32) -> BN+ReLU(32)
    k_gemm2<32, 2><<<dim3(mg, 1), 256, 0, stream>>>(bufB, W4, bufA, NN, 64, 32);
    k_spmm4<32><<<(NN + 31) / 32, 256, 0, stream>>>(rowptr, col, val, bufA, bufB);
    k_bn_stats<<<(NN + 63) / 64, 32, 0, stream>>>(bufB, stats + 3 * 512, 32);
    k_bn_final<<<1, 32, 0, stream>>>(stats + 3 * 512, g4, be4, ac, 32);
    k_bn_apply<<<(int)(((long)NN * 32 + 255) / 256), 256, 0, stream>>>(bufB, ac, 32);

    // ---- fused pool + head
    k_pool2<<<NG, 256, 0, stream>>>(bufB, gstart, Wl, bl, out);
}

// Round 3
// 738.373 us; speedup vs baseline: 1.8624x; 1.1128x over previous
//
#include <hip/hip_runtime.h>
#include <cstdint>
#include <cstddef>

#define NN 50000            // nodes
#define NNP 50176           // padded rows (GEMM tile overreach stays in-bounds)
#define NE 800000           // edges (before self loops)
#define NT (NE + NN)        // edges incl self loops
#define NG 64               // graphs
#define BN_EPS 1e-5f

typedef unsigned int u32;
typedef unsigned short u16;

using short8 = __attribute__((ext_vector_type(8))) short;  // 8 bf16 (4 VGPRs)
using f32x4  = __attribute__((ext_vector_type(4))) float;

__device__ __forceinline__ float bf_lo(u32 u) { return __builtin_bit_cast(float, u << 16); }
__device__ __forceinline__ float bf_hi(u32 u) { return __builtin_bit_cast(float, u & 0xffff0000u); }
__device__ __forceinline__ u32 f2bf(float f) {           // RNE float->bf16
    u32 u = __builtin_bit_cast(u32, f);
    return (u + 0x7fffu + ((u >> 16) & 1u)) >> 16;
}
__device__ __forceinline__ u32 pack2(float a, float b) { return f2bf(a) | (f2bf(b) << 16); }

__device__ __forceinline__ void gload16(const void* g, void* lds) {
    __builtin_amdgcn_global_load_lds((const __attribute__((address_space(1))) u32*)g,
                                     (__attribute__((address_space(3))) u32*)lds, 16, 0, 0);
}

// ---------------------------------------------------------------------------
// int64-vs-int32 detection for edge_index / batch
__global__ void k_detect(const int* __restrict__ ei, int* __restrict__ flag) {
    if (blockIdx.x == 0 && threadIdx.x == 0) {
        int is64 = (ei[1] == 0 && ei[3] == 0 && ei[5] == 0 && ei[7] == 0) ? 1 : 0;
        *flag = is64;
    }
}

__device__ __forceinline__ int ld_idx(const int* __restrict__ p, long i, int is64) {
    return is64 ? p[2 * i] : p[i];
}

// ---------------------------------------------------------------------------
__global__ void k_deg_count(const int* __restrict__ ei, const float* __restrict__ ew,
                            const int* __restrict__ flag,
                            float* __restrict__ deg, int* __restrict__ cnt) {
    const int is64 = *flag;
    int i = blockIdx.x * 256 + threadIdx.x;
    const int stride = gridDim.x * 256;
    for (; i < NT; i += stride) {
        int d; float w;
        if (i < NE) { d = ld_idx(ei, (long)NE + i, is64); w = ew[i]; }
        else        { d = i - NE;                          w = 1.0f;  }
        atomicAdd(&deg[d], w);
        atomicAdd(&cnt[d], 1);
    }
}

// exclusive prefix sum of cnt -> rowptr (and cursor copy). single block.
__global__ void k_scan(const int* __restrict__ cnt, int* __restrict__ rowptr,
                       int* __restrict__ cursor) {
    __shared__ int warp_excl[16];
    __shared__ int s_base;
    __shared__ int s_chunk_total;
    const int tid  = threadIdx.x;
    const int lane = tid & 63;
    const int wid  = tid >> 6;
    if (tid == 0) s_base = 0;
    __syncthreads();
    for (int start = 0; start < NN; start += 1024) {
        const int idx = start + tid;
        const int v = (idx < NN) ? cnt[idx] : 0;
        int s = v;
        #pragma unroll
        for (int off = 1; off < 64; off <<= 1) {
            int t = __shfl_up(s, off, 64);
            if (lane >= off) s += t;
        }
        if (lane == 63) warp_excl[wid] = s;
        __syncthreads();
        if (tid == 0) {
            int acc = 0;
            #pragma unroll
            for (int w = 0; w < 16; ++w) { int t = warp_excl[w]; warp_excl[w] = acc; acc += t; }
        }
        __syncthreads();
        const int incl = s + warp_excl[wid];
        if (tid == 1023) s_chunk_total = incl;
        const int excl = incl - v;
        if (idx < NN) { const int r = s_base + excl; rowptr[idx] = r; cursor[idx] = r; }
        __syncthreads();
        if (tid == 0) s_base += s_chunk_total;
        __syncthreads();
    }
    if (tid == 0) rowptr[NN] = s_base;
}

__global__ void k_dis(const float* __restrict__ deg, float* __restrict__ dis) {
    const int i = blockIdx.x * 256 + threadIdx.x;
    if (i < NN) dis[i] = deg[i] > 0.0f ? rsqrtf(deg[i]) : 0.0f;
}

__global__ void k_csr(const int* __restrict__ ei, const float* __restrict__ ew,
                      const int* __restrict__ flag, const float* __restrict__ dis,
                      int* __restrict__ cursor, int* __restrict__ col,
                      float* __restrict__ val) {
    const int is64 = *flag;
    int i = blockIdx.x * 256 + threadIdx.x;
    const int stride = gridDim.x * 256;
    for (; i < NT; i += stride) {
        int s, d; float w;
        if (i < NE) { s = ld_idx(ei, i, is64); d = ld_idx(ei, (long)NE + i, is64); w = ew[i]; }
        else        { s = d = i - NE;          w = 1.0f;  }
        const int pos = atomicAdd(&cursor[d], 1);
        col[pos] = s;
        val[pos] = dis[s] * w * dis[d];
    }
}

__global__ void k_bounds(const int* __restrict__ batch, const int* __restrict__ flag,
                         int* __restrict__ gstart) {
    const int g = threadIdx.x;
    if (g > NG) return;
    const int is64 = *flag;
    int lo = 0, hi = NN;
    while (lo < hi) {
        const int mid = (lo + hi) >> 1;
        if (ld_idx(batch, mid, is64) < g) lo = mid + 1; else hi = mid;
    }
    gstart[g] = lo;
}

// ---------------------------------------------------------------------------
// conversions
__global__ void k_cvt(const float* __restrict__ x, u16* __restrict__ xb) {
    const size_t i = ((size_t)blockIdx.x * 256 + threadIdx.x) * 8;
    if (i >= (size_t)NN * 128) return;
    const float4 a = *(const float4*)(x + i);
    const float4 b = *(const float4*)(x + i + 4);
    uint4 o;
    o.x = pack2(a.x, a.y); o.y = pack2(a.z, a.w);
    o.z = pack2(b.x, b.y); o.w = pack2(b.z, b.w);
    *(uint4*)(xb + i) = o;
}

// W[K][N] fp32 -> Wt[N][K] bf16
__global__ void k_wt(const float* __restrict__ W, u16* __restrict__ Wt, int Kd, int Nd) {
    const int i = blockIdx.x * 256 + threadIdx.x;
    if (i >= Kd * Nd) return;
    const int k = i / Nd, n = i % Nd;
    Wt[(size_t)n * Kd + k] = (u16)f2bf(W[i]);
}

// ---------------------------------------------------------------------------
// SpMM bf16: out[v][f] = sum_e val[e] * x[col[e]][f]; 8 feats/lane, fp32 acc
template <int F>
__global__ void k_spmm_bf(const int* __restrict__ rowptr, const int* __restrict__ col,
                          const float* __restrict__ val, const u16* __restrict__ x,
                          u16* __restrict__ out) {
    constexpr int L = F / 8;
    constexpr int NPB = 256 / L;
    const int node = blockIdx.x * NPB + threadIdx.x / L;
    const int q = threadIdx.x % L;
    if (node >= NN) return;
    const int beg = rowptr[node], end = rowptr[node + 1];
    float a0 = 0, a1 = 0, a2 = 0, a3 = 0, a4 = 0, a5 = 0, a6 = 0, a7 = 0;
    for (int e = beg; e < end; ++e) {
        const int s = col[e];
        const float v = val[e];
        const uint4 xv = *(const uint4*)(x + (size_t)s * F + q * 8);
        a0 += v * bf_lo(xv.x); a1 += v * bf_hi(xv.x);
        a2 += v * bf_lo(xv.y); a3 += v * bf_hi(xv.y);
        a4 += v * bf_lo(xv.z); a5 += v * bf_hi(xv.z);
        a6 += v * bf_lo(xv.w); a7 += v * bf_hi(xv.w);
    }
    uint4 o;
    o.x = pack2(a0, a1); o.y = pack2(a2, a3);
    o.z = pack2(a4, a5); o.w = pack2(a6, a7);
    *(uint4*)(out + (size_t)node * F + q * 8) = o;
}

// ---------------------------------------------------------------------------
// bf16 MFMA GEMM: C[M,N] = A[M,K] @ Wt[N,K]^T, all bf16, fp32 accum.
// Block: 256 thr (4 waves), tile 128 x BN. Whole Wt tile [BN][K] in LDS
// (XOR-swizzled); A staged 128x32 per K-step via global_load_lds with
// pre-swizzled global source (linear LDS dest), double-buffered.
template <int K, int BN>
__global__ void k_gemm_bf(const u16* __restrict__ A, const u16* __restrict__ Wt,
                          u16* __restrict__ C, int M, int N) {
    constexpr int KS = K / 8;        // 16B slots per Wt row
    constexpr int CT = BN / 16;      // col tiles per block
    __shared__ alignas(16) u16 sW[BN * K];
    __shared__ alignas(16) u16 sA[2][128 * 32];
    const int tid  = threadIdx.x;
    const int lane = tid & 63;
    const int w    = tid >> 6;
    const int m0 = blockIdx.x * 128;
    const int n0 = blockIdx.y * BN;

    // stage whole Wt tile [BN][K]: phys slot s holds logical slot s^(row&7)
    #pragma unroll
    for (int i = 0; i < (BN * KS) / 256; ++i) {
        const int u = i * 256 + tid;
        const int r = u / KS;
        const int s = u % KS;
        const int ls = s ^ (r & 7);
        gload16(Wt + (size_t)(n0 + r) * K + ls * 8,
                (char*)sW + (i * 256 + w * 64) * 16);
    }
    // stage A chunk [128][32]: phys slot s holds logical slot s^((row>>1)&3)
    auto stageA = [&](int buf, int kt) {
        #pragma unroll
        for (int i = 0; i < 2; ++i) {
            const int u = i * 256 + tid;
            const int r = u >> 2;
            const int s = u & 3;
            const int ls = s ^ ((r >> 1) & 3);
            gload16(A + (size_t)(m0 + r) * K + kt + ls * 8,
                    (char*)&sA[buf][0] + (i * 256 + w * 64) * 16);
        }
    };
    stageA(0, 0);
    __syncthreads();

    f32x4 acc[2][CT] = {};
    const int rl  = lane & 15;
    const int k16 = lane >> 4;
    for (int ki = 0; ki < K / 32; ++ki) {
        if (ki + 1 < K / 32) stageA((ki + 1) & 1, (ki + 1) * 32);
        short8 af[2], bfr[CT];
        #pragma unroll
        for (int rt = 0; rt < 2; ++rt) {
            const int row = w * 32 + rt * 16 + rl;
            const int p = k16 ^ ((row >> 1) & 3);
            af[rt] = *(const short8*)((const char*)&sA[ki & 1][0] + row * 64 + p * 16);
        }
        #pragma unroll
        for (int ct = 0; ct < CT; ++ct) {
            const int c = ct * 16 + rl;
            const int p = (ki * 4 + k16) ^ (c & 7);
            bfr[ct] = *(const short8*)((const char*)sW + c * (K * 2) + p * 16);
        }
        #pragma unroll
        for (int rt = 0; rt < 2; ++rt)
            #pragma unroll
            for (int ct = 0; ct < CT; ++ct)
                acc[rt][ct] = __builtin_amdgcn_mfma_f32_16x16x32_bf16(af[rt], bfr[ct], acc[rt][ct], 0, 0, 0);
        __syncthreads();
    }

    // D[(lane>>4)*4 + r][lane&15] per 16x16 tile (verified layout)
    #pragma unroll
    for (int rt = 0; rt < 2; ++rt) {
        #pragma unroll
        for (int r = 0; r < 4; ++r) {
            const int row = m0 + w * 32 + rt * 16 + k16 * 4 + r;
            if (row < M) {
                #pragma unroll
                for (int ct = 0; ct < CT; ++ct)
                    C[(size_t)row * N + n0 + ct * 16 + rl] = (u16)f2bf(acc[rt][ct][r]);
            }
        }
    }
}

// ---------------------------------------------------------------------------
// BN stats from bf16 buffer
template <int F>
__global__ void k_bn_stats_bf(const u16* __restrict__ x, float* __restrict__ stats) {
    constexpr int G = 256 / F;
    const int f = threadIdx.x % F;
    const int sub = threadIdx.x / F;
    const int r0 = blockIdx.x * 128;
    const int r1 = (r0 + 128 < NN) ? r0 + 128 : NN;
    float s = 0.0f, ss = 0.0f;
    for (int r = r0 + sub; r < r1; r += G) {
        const float v = bf_lo((u32)x[(size_t)r * F + f]);
        s += v; ss += v * v;
    }
    atomicAdd(&stats[f], s);
    atomicAdd(&stats[F + f], ss);
}

__global__ void k_bn_final(const float* __restrict__ stats, const float* __restrict__ g,
                           const float* __restrict__ be, float* __restrict__ ac, int F) {
    const int f = threadIdx.x;
    if (f >= F) return;
    const float mu  = stats[f] * (1.0f / NN);
    const float var = stats[F + f] * (1.0f / NN) - mu * mu;
    const float a = g[f] * rsqrtf(var + BN_EPS);
    ac[f]     = a;
    ac[F + f] = be[f] - mu * a;
}

template <int F>
__global__ void k_bn_apply_bf(u16* __restrict__ x, const float* __restrict__ ac) {
    const size_t i = ((size_t)blockIdx.x * 256 + threadIdx.x) * 8;
    if (i >= (size_t)NN * F) return;
    const int f0 = (int)(i & (F - 1));
    uint4 v = *(uint4*)(x + i);
    float y0 = bf_lo(v.x), y1 = bf_hi(v.x), y2 = bf_lo(v.y), y3 = bf_hi(v.y);
    float y4 = bf_lo(v.z), y5 = bf_hi(v.z), y6 = bf_lo(v.w), y7 = bf_hi(v.w);
    float t;
    t = y0 * ac[f0 + 0] + ac[F + f0 + 0]; y0 = t > 0.f ? t : 0.f;
    t = y1 * ac[f0 + 1] + ac[F + f0 + 1]; y1 = t > 0.f ? t : 0.f;
    t = y2 * ac[f0 + 2] + ac[F + f0 + 2]; y2 = t > 0.f ? t : 0.f;
    t = y3 * ac[f0 + 3] + ac[F + f0 + 3]; y3 = t > 0.f ? t : 0.f;
    t = y4 * ac[f0 + 4] + ac[F + f0 + 4]; y4 = t > 0.f ? t : 0.f;
    t = y5 * ac[f0 + 5] + ac[F + f0 + 5]; y5 = t > 0.f ? t : 0.f;
    t = y6 * ac[f0 + 6] + ac[F + f0 + 6]; y6 = t > 0.f ? t : 0.f;
    t = y7 * ac[f0 + 7] + ac[F + f0 + 7]; y7 = t > 0.f ? t : 0.f;
    uint4 o;
    o.x = pack2(y0, y1); o.y = pack2(y2, y3);
    o.z = pack2(y4, y5); o.w = pack2(y6, y7);
    *(uint4*)(x + i) = o;
}

// ---------------------------------------------------------------------------
// fused mean-pool + linear head + sigmoid (bf16 input)
__global__ void k_pool_bf(const u16* __restrict__ h, const int* __restrict__ gstart,
                          const float* __restrict__ Wl, const float* __restrict__ bl,
                          float* __restrict__ out) {
    const int g = blockIdx.x;
    const int s = gstart[g], e = gstart[g + 1];
    const int f = threadIdx.x & 31, c = threadIdx.x >> 5;
    float acc = 0.0f;
    for (int r = s + c; r < e; r += 8) acc += bf_lo((u32)h[(size_t)r * 32 + f]);
    __shared__ float red[8][32];
    red[c][f] = acc;
    __syncthreads();
    if (threadIdx.x < 32) {
        float t = 0.0f;
        #pragma unroll
        for (int i = 0; i < 8; ++i) t += red[i][f];
        float cntf = (float)(e - s);
        cntf = cntf > 1.0f ? cntf : 1.0f;
        float p = (t / cntf) * Wl[f];
        #pragma unroll
        for (int off = 16; off > 0; off >>= 1) p += __shfl_down(p, off, 32);
        if (f == 0) out[g] = 1.0f / (1.0f + expf(-(p + bl[0])));
    }
}

// ---------------------------------------------------------------------------
extern "C" void kernel_launch(void* const* d_in, const int* in_sizes, int n_in,
                              void* d_out, int out_size, void* d_ws, size_t ws_size,
                              hipStream_t stream) {
    const float* x     = (const float*)d_in[0];
    const int*   ei    = (const int*)d_in[1];
    const float* ew    = (const float*)d_in[2];
    const int*   batch = (const int*)d_in[3];
    const float* W1 = (const float*)d_in[4];
    const float* g1 = (const float*)d_in[6];
    const float* be1 = (const float*)d_in[7];
    const float* W2 = (const float*)d_in[8];
    const float* g2 = (const float*)d_in[10];
    const float* be2 = (const float*)d_in[11];
    const float* W3 = (const float*)d_in[12];
    const float* g3 = (const float*)d_in[14];
    const float* be3 = (const float*)d_in[15];
    const float* W4 = (const float*)d_in[16];
    const float* g4 = (const float*)d_in[18];
    const float* be4 = (const float*)d_in[19];
    const float* Wl = (const float*)d_in[20];
    const float* bl = (const float*)d_in[21];
    float* out = (float*)d_out;

    char* ws = (char*)d_ws;
    size_t off = 0;
    auto alloc = [&](size_t bytes) -> void* {
        void* p = ws + off;
        off += (bytes + 255) & ~(size_t)255;
        return p;
    };
    // zeroed region first (one memset)
    float* deg   = (float*)alloc((size_t)NN * 4);
    int*   cnt   = (int*)  alloc((size_t)NN * 4);
    float* stats = (float*)alloc(4 * 512 * 4);
    const size_t zero_bytes = off;
    // non-zeroed
    int*   flag   = (int*)  alloc(256);
    float* ac     = (float*)alloc(512 * 4);
    int*   gstart = (int*)  alloc((NG + 1) * 4);
    int*   rowptr = (int*)  alloc((size_t)(NN + 1) * 4);
    int*   cursor = (int*)  alloc((size_t)NN * 4);
    float* dis    = (float*)alloc((size_t)NN * 4);
    int*   col    = (int*)  alloc((size_t)NT * 4);
    float* val    = (float*)alloc((size_t)NT * 4);
    u16*   xb     = (u16*)  alloc((size_t)NNP * 128 * 2);
    u16*   wt1    = (u16*)  alloc((size_t)256 * 128 * 2);
    u16*   wt2    = (u16*)  alloc((size_t)128 * 256 * 2);
    u16*   wt3    = (u16*)  alloc((size_t)64 * 128 * 2);
    u16*   wt4    = (u16*)  alloc((size_t)32 * 64 * 2);
    u16*   bufA   = (u16*)  alloc((size_t)NNP * 256 * 2);
    u16*   bufB   = (u16*)  alloc((size_t)NNP * 256 * 2);

    hipMemsetAsync(d_ws, 0, zero_bytes, stream);

    const int egrid = (NT + 255) / 256;
    const int mg = (NN + 127) / 128;     // GEMM grid.x

    k_detect<<<1, 64, 0, stream>>>(ei, flag);
    k_deg_count<<<egrid, 256, 0, stream>>>(ei, ew, flag, deg, cnt);
    k_scan<<<1, 1024, 0, stream>>>(cnt, rowptr, cursor);
    k_dis<<<(NN + 255) / 256, 256, 0, stream>>>(deg, dis);
    k_csr<<<egrid, 256, 0, stream>>>(ei, ew, flag, dis, cursor, col, val);
    k_bounds<<<1, 128, 0, stream>>>(batch, flag, gstart);

    k_cvt<<<(int)(((size_t)NN * 128 / 8 + 255) / 256), 256, 0, stream>>>(x, xb);
    k_wt<<<(128 * 256 + 255) / 256, 256, 0, stream>>>(W1, wt1, 128, 256);
    k_wt<<<(256 * 128 + 255) / 256, 256, 0, stream>>>(W2, wt2, 256, 128);
    k_wt<<<(128 * 64 + 255) / 256, 256, 0, stream>>>(W3, wt3, 128, 64);
    k_wt<<<(64 * 32 + 255) / 256, 256, 0, stream>>>(W4, wt4, 64, 32);

    // ---- layer 1: aggregate(128) -> GEMM 128->256 -> BN+ReLU
    k_spmm_bf<128><<<(NN + 15) / 16, 256, 0, stream>>>(rowptr, col, val, xb, bufA);
    k_gemm_bf<128, 64><<<dim3(mg, 4), 256, 0, stream>>>(bufA, wt1, bufB, NN, 256);
    k_bn_stats_bf<256><<<(NN + 127) / 128, 256, 0, stream>>>(bufB, stats + 0 * 512);
    k_bn_final<<<1, 256, 0, stream>>>(stats + 0 * 512, g1, be1, ac, 256);
    k_bn_apply_bf<256><<<(int)(((size_t)NN * 256 / 8 + 255) / 256), 256, 0, stream>>>(bufB, ac);

    // ---- layer 2: GEMM 256->128 -> aggregate(128) -> BN+ReLU
    k_gemm_bf<256, 64><<<dim3(mg, 2), 256, 0, stream>>>(bufB, wt2, bufA, NN, 128);
    k_spmm_bf<128><<<(NN + 15) / 16, 256, 0, stream>>>(rowptr, col, val, bufA, bufB);
    k_bn_stats_bf<128><<<(NN + 127) / 128, 256, 0, stream>>>(bufB, stats + 1 * 512);
    k_bn_final<<<1, 128, 0, stream>>>(stats + 1 * 512, g2, be2, ac, 128);
    k_bn_apply_bf<128><<<(int)(((size_t)NN * 128 / 8 + 255) / 256), 256, 0, stream>>>(bufB, ac);

    // ---- layer 3: GEMM 128->64 -> aggregate(64) -> BN+ReLU
    k_gemm_bf<128, 64><<<dim3(mg, 1), 256, 0, stream>>>(bufB, wt3, bufA, NN, 64);
    k_spmm_bf<64><<<(NN + 31) / 32, 256, 0, stream>>>(rowptr, col, val, bufA, bufB);
    k_bn_stats_bf<64><<<(NN + 127) / 128, 256, 0, stream>>>(bufB, stats + 2 * 512);
    k_bn_final<<<1, 64, 0, stream>>>(stats + 2 * 512, g3, be3, ac, 64);
    k_bn_apply_bf<64><<<(int)(((size_t)NN * 64 / 8 + 255) / 256), 256, 0, stream>>>(bufB, ac);

    // ---- layer 4: GEMM 64->32 -> aggregate(32) -> BN+ReLU
    k_gemm_bf<64, 32><<<dim3(mg, 1), 256, 0, stream>>>(bufB, wt4, bufA, NN, 32);
    k_spmm_bf<32><<<(NN + 63) / 64, 256, 0, stream>>>(rowptr, col, val, bufA, bufB);
    k_bn_stats_bf<32><<<(NN + 127) / 128, 256, 0, stream>>>(bufB, stats + 3 * 512);
    k_bn_final<<<1, 64, 0, stream>>>(stats + 3 * 512, g4, be4, ac, 32);
    k_bn_apply_bf<32><<<(int)(((size_t)NN * 32 / 8 + 255) / 256), 256, 0, stream>>>(bufB, ac);

    // ---- fused pool + head
    k_pool_bf<<<NG, 256, 0, stream>>>(bufB, gstart, Wl, bl, out);
}

// Round 4
// 541.340 us; speedup vs baseline: 2.5402x; 1.3640x over previous
//
#include <hip/hip_runtime.h>
#include <cstdint>
#include <cstddef>

#define NN 50000            // nodes
#define NNP 50176           // padded rows (GEMM tile overreach stays in-bounds)
#define NE 800000           // edges (before self loops)
#define NT (NE + NN)        // edges incl self loops
#define NG 64               // graphs
#define BN_EPS 1e-5f
#define NBLK_ST 500         // BN-stats blocks
#define ROWS_ST 100         // rows per BN-stats block (500*100 = 50000)

typedef unsigned int u32;
typedef unsigned short u16;

using short8 = __attribute__((ext_vector_type(8))) short;  // 8 bf16 (4 VGPRs)
using f32x4  = __attribute__((ext_vector_type(4))) float;

__device__ __forceinline__ float bf_lo(u32 u) { return __builtin_bit_cast(float, u << 16); }
__device__ __forceinline__ float bf_hi(u32 u) { return __builtin_bit_cast(float, u & 0xffff0000u); }
__device__ __forceinline__ u32 f2bf(float f) {           // RNE float->bf16
    u32 u = __builtin_bit_cast(u32, f);
    return (u + 0x7fffu + ((u >> 16) & 1u)) >> 16;
}
__device__ __forceinline__ u32 pack2(float a, float b) { return f2bf(a) | (f2bf(b) << 16); }

__device__ __forceinline__ void gload16(const void* g, void* lds) {
    __builtin_amdgcn_global_load_lds((const __attribute__((address_space(1))) u32*)g,
                                     (__attribute__((address_space(3))) u32*)lds, 16, 0, 0);
}

// ---------------------------------------------------------------------------
// int64-vs-int32 detection for edge_index / batch
__global__ void k_detect(const int* __restrict__ ei, int* __restrict__ flag) {
    if (blockIdx.x == 0 && threadIdx.x == 0) {
        int is64 = (ei[1] == 0 && ei[3] == 0 && ei[5] == 0 && ei[7] == 0) ? 1 : 0;
        *flag = is64;
    }
}

__device__ __forceinline__ int ld_idx(const int* __restrict__ p, long i, int is64) {
    return is64 ? p[2 * i] : p[i];
}

// ---------------------------------------------------------------------------
__global__ void k_deg_count(const int* __restrict__ ei, const float* __restrict__ ew,
                            const int* __restrict__ flag,
                            float* __restrict__ deg, int* __restrict__ cnt) {
    const int is64 = *flag;
    int i = blockIdx.x * 256 + threadIdx.x;
    const int stride = gridDim.x * 256;
    for (; i < NT; i += stride) {
        int d; float w;
        if (i < NE) { d = ld_idx(ei, (long)NE + i, is64); w = ew[i]; }
        else        { d = i - NE;                          w = 1.0f;  }
        atomicAdd(&deg[d], w);
        atomicAdd(&cnt[d], 1);
    }
}

// exclusive prefix sum of cnt -> rowptr (and cursor copy). single block.
__global__ void k_scan(const int* __restrict__ cnt, int* __restrict__ rowptr,
                       int* __restrict__ cursor) {
    __shared__ int warp_excl[16];
    __shared__ int s_base;
    __shared__ int s_chunk_total;
    const int tid  = threadIdx.x;
    const int lane = tid & 63;
    const int wid  = tid >> 6;
    if (tid == 0) s_base = 0;
    __syncthreads();
    for (int start = 0; start < NN; start += 1024) {
        const int idx = start + tid;
        const int v = (idx < NN) ? cnt[idx] : 0;
        int s = v;
        #pragma unroll
        for (int off = 1; off < 64; off <<= 1) {
            int t = __shfl_up(s, off, 64);
            if (lane >= off) s += t;
        }
        if (lane == 63) warp_excl[wid] = s;
        __syncthreads();
        if (tid == 0) {
            int acc = 0;
            #pragma unroll
            for (int w = 0; w < 16; ++w) { int t = warp_excl[w]; warp_excl[w] = acc; acc += t; }
        }
        __syncthreads();
        const int incl = s + warp_excl[wid];
        if (tid == 1023) s_chunk_total = incl;
        const int excl = incl - v;
        if (idx < NN) { const int r = s_base + excl; rowptr[idx] = r; cursor[idx] = r; }
        __syncthreads();
        if (tid == 0) s_base += s_chunk_total;
        __syncthreads();
    }
    if (tid == 0) rowptr[NN] = s_base;
}

__global__ void k_dis(const float* __restrict__ deg, float* __restrict__ dis) {
    const int i = blockIdx.x * 256 + threadIdx.x;
    if (i < NN) dis[i] = deg[i] > 0.0f ? rsqrtf(deg[i]) : 0.0f;
}

__global__ void k_csr(const int* __restrict__ ei, const float* __restrict__ ew,
                      const int* __restrict__ flag, const float* __restrict__ dis,
                      int* __restrict__ cursor, int* __restrict__ col,
                      float* __restrict__ val) {
    const int is64 = *flag;
    int i = blockIdx.x * 256 + threadIdx.x;
    const int stride = gridDim.x * 256;
    for (; i < NT; i += stride) {
        int s, d; float w;
        if (i < NE) { s = ld_idx(ei, i, is64); d = ld_idx(ei, (long)NE + i, is64); w = ew[i]; }
        else        { s = d = i - NE;          w = 1.0f;  }
        const int pos = atomicAdd(&cursor[d], 1);
        col[pos] = s;
        val[pos] = dis[s] * w * dis[d];
    }
}

__global__ void k_bounds(const int* __restrict__ batch, const int* __restrict__ flag,
                         int* __restrict__ gstart) {
    const int g = threadIdx.x;
    if (g > NG) return;
    const int is64 = *flag;
    int lo = 0, hi = NN;
    while (lo < hi) {
        const int mid = (lo + hi) >> 1;
        if (ld_idx(batch, mid, is64) < g) lo = mid + 1; else hi = mid;
    }
    gstart[g] = lo;
}

// ---------------------------------------------------------------------------
// conversions
__global__ void k_cvt(const float* __restrict__ x, u16* __restrict__ xb) {
    const size_t i = ((size_t)blockIdx.x * 256 + threadIdx.x) * 8;
    if (i >= (size_t)NN * 128) return;
    const float4 a = *(const float4*)(x + i);
    const float4 b = *(const float4*)(x + i + 4);
    uint4 o;
    o.x = pack2(a.x, a.y); o.y = pack2(a.z, a.w);
    o.z = pack2(b.x, b.y); o.w = pack2(b.z, b.w);
    *(uint4*)(xb + i) = o;
}

// W[K][N] fp32 -> Wt[N][K] bf16
__global__ void k_wt(const float* __restrict__ W, u16* __restrict__ Wt, int Kd, int Nd) {
    const int i = blockIdx.x * 256 + threadIdx.x;
    if (i >= Kd * Nd) return;
    const int k = i / Nd, n = i % Nd;
    Wt[(size_t)n * Kd + k] = (u16)f2bf(W[i]);
}

// ---------------------------------------------------------------------------
// SpMM bf16: out[v][f] = sum_e val[e] * x[col[e]][f]; 8 feats/lane, fp32 acc
template <int F>
__global__ void k_spmm_bf(const int* __restrict__ rowptr, const int* __restrict__ col,
                          const float* __restrict__ val, const u16* __restrict__ x,
                          u16* __restrict__ out) {
    constexpr int L = F / 8;
    constexpr int NPB = 256 / L;
    const int node = blockIdx.x * NPB + threadIdx.x / L;
    const int q = threadIdx.x % L;
    if (node >= NN) return;
    const int beg = rowptr[node], end = rowptr[node + 1];
    float a0 = 0, a1 = 0, a2 = 0, a3 = 0, a4 = 0, a5 = 0, a6 = 0, a7 = 0;
    for (int e = beg; e < end; ++e) {
        const int s = col[e];
        const float v = val[e];
        const uint4 xv = *(const uint4*)(x + (size_t)s * F + q * 8);
        a0 += v * bf_lo(xv.x); a1 += v * bf_hi(xv.x);
        a2 += v * bf_lo(xv.y); a3 += v * bf_hi(xv.y);
        a4 += v * bf_lo(xv.z); a5 += v * bf_hi(xv.z);
        a6 += v * bf_lo(xv.w); a7 += v * bf_hi(xv.w);
    }
    uint4 o;
    o.x = pack2(a0, a1); o.y = pack2(a2, a3);
    o.z = pack2(a4, a5); o.w = pack2(a6, a7);
    *(uint4*)(out + (size_t)node * F + q * 8) = o;
}

// ---------------------------------------------------------------------------
// bf16 MFMA GEMM: C[M,N] = A[M,K] @ Wt[N,K]^T, all bf16, fp32 accum.
template <int K, int BN>
__global__ void k_gemm_bf(const u16* __restrict__ A, const u16* __restrict__ Wt,
                          u16* __restrict__ C, int M, int N) {
    constexpr int KS = K / 8;        // 16B slots per Wt row
    constexpr int CT = BN / 16;      // col tiles per block
    __shared__ alignas(16) u16 sW[BN * K];
    __shared__ alignas(16) u16 sA[2][128 * 32];
    const int tid  = threadIdx.x;
    const int lane = tid & 63;
    const int w    = tid >> 6;
    const int m0 = blockIdx.x * 128;
    const int n0 = blockIdx.y * BN;

    // stage whole Wt tile [BN][K]: phys slot s holds logical slot s^(row&7)
    #pragma unroll
    for (int i = 0; i < (BN * KS) / 256; ++i) {
        const int u = i * 256 + tid;
        const int r = u / KS;
        const int s = u % KS;
        const int ls = s ^ (r & 7);
        gload16(Wt + (size_t)(n0 + r) * K + ls * 8,
                (char*)sW + (i * 256 + w * 64) * 16);
    }
    // stage A chunk [128][32]: phys slot s holds logical slot s^((row>>1)&3)
    auto stageA = [&](int buf, int kt) {
        #pragma unroll
        for (int i = 0; i < 2; ++i) {
            const int u = i * 256 + tid;
            const int r = u >> 2;
            const int s = u & 3;
            const int ls = s ^ ((r >> 1) & 3);
            gload16(A + (size_t)(m0 + r) * K + kt + ls * 8,
                    (char*)&sA[buf][0] + (i * 256 + w * 64) * 16);
        }
    };
    stageA(0, 0);
    __syncthreads();

    f32x4 acc[2][CT] = {};
    const int rl  = lane & 15;
    const int k16 = lane >> 4;
    for (int ki = 0; ki < K / 32; ++ki) {
        if (ki + 1 < K / 32) stageA((ki + 1) & 1, (ki + 1) * 32);
        short8 af[2], bfr[CT];
        #pragma unroll
        for (int rt = 0; rt < 2; ++rt) {
            const int row = w * 32 + rt * 16 + rl;
            const int p = k16 ^ ((row >> 1) & 3);
            af[rt] = *(const short8*)((const char*)&sA[ki & 1][0] + row * 64 + p * 16);
        }
        #pragma unroll
        for (int ct = 0; ct < CT; ++ct) {
            const int c = ct * 16 + rl;
            const int p = (ki * 4 + k16) ^ (c & 7);
            bfr[ct] = *(const short8*)((const char*)sW + c * (K * 2) + p * 16);
        }
        #pragma unroll
        for (int rt = 0; rt < 2; ++rt)
            #pragma unroll
            for (int ct = 0; ct < CT; ++ct)
                acc[rt][ct] = __builtin_amdgcn_mfma_f32_16x16x32_bf16(af[rt], bfr[ct], acc[rt][ct], 0, 0, 0);
        __syncthreads();
    }

    #pragma unroll
    for (int rt = 0; rt < 2; ++rt) {
        #pragma unroll
        for (int r = 0; r < 4; ++r) {
            const int row = m0 + w * 32 + rt * 16 + k16 * 4 + r;
            if (row < M) {
                #pragma unroll
                for (int ct = 0; ct < CT; ++ct)
                    C[(size_t)row * N + n0 + ct * 16 + rl] = (u16)f2bf(acc[rt][ct][r]);
            }
        }
    }
}

// ---------------------------------------------------------------------------
// BN stats phase A: per-block partial sum/sumsq, vectorized, no global atomics.
// 500 blocks x 100 rows; thread owns 8 consecutive cols (uint4 load).
template <int F>
__global__ void k_bn_stats2(const u16* __restrict__ x, float* __restrict__ P) {
    constexpr int LPR = F / 8;            // lanes per row
    constexpr int RPI = 256 / LPR;        // rows processed per iteration
    const int f8  = threadIdx.x % LPR;
    const int sub = threadIdx.x / LPR;
    const int r0 = blockIdx.x * ROWS_ST;
    int r1 = r0 + ROWS_ST; if (r1 > NN) r1 = NN;
    float s[8] = {}, ss[8] = {};
    for (int r = r0 + sub; r < r1; r += RPI) {
        const uint4 v = *(const uint4*)(x + (size_t)r * F + f8 * 8);
        float y;
        y = bf_lo(v.x); s[0] += y; ss[0] += y * y;
        y = bf_hi(v.x); s[1] += y; ss[1] += y * y;
        y = bf_lo(v.y); s[2] += y; ss[2] += y * y;
        y = bf_hi(v.y); s[3] += y; ss[3] += y * y;
        y = bf_lo(v.z); s[4] += y; ss[4] += y * y;
        y = bf_hi(v.z); s[5] += y; ss[5] += y * y;
        y = bf_lo(v.w); s[6] += y; ss[6] += y * y;
        y = bf_hi(v.w); s[7] += y; ss[7] += y * y;
    }
    __shared__ float ls[2 * F];
    for (int i = threadIdx.x; i < 2 * F; i += 256) ls[i] = 0.0f;
    __syncthreads();
    #pragma unroll
    for (int j = 0; j < 8; ++j) {
        atomicAdd(&ls[f8 * 8 + j], s[j]);
        atomicAdd(&ls[F + f8 * 8 + j], ss[j]);
    }
    __syncthreads();
    float* Pb = P + (size_t)blockIdx.x * (2 * F);
    for (int i = threadIdx.x; i < 2 * F; i += 256) Pb[i] = ls[i];
}

// BN stats phase B: reduce partials + produce fused affine coefficients.
template <int F>
__global__ void k_bn_red(const float* __restrict__ P, const float* __restrict__ g,
                         const float* __restrict__ be, float* __restrict__ ac) {
    const int f = threadIdx.x;
    if (f >= F) return;
    float s = 0.0f, ss = 0.0f;
    for (int b = 0; b < NBLK_ST; ++b) {
        s  += P[(size_t)b * (2 * F) + f];
        ss += P[(size_t)b * (2 * F) + F + f];
    }
    const float mu  = s * (1.0f / NN);
    const float var = ss * (1.0f / NN) - mu * mu;
    const float a = g[f] * rsqrtf(var + BN_EPS);
    ac[f]     = a;
    ac[F + f] = be[f] - mu * a;
}

template <int F>
__global__ void k_bn_apply_bf(u16* __restrict__ x, const float* __restrict__ ac) {
    const size_t i = ((size_t)blockIdx.x * 256 + threadIdx.x) * 8;
    if (i >= (size_t)NN * F) return;
    const int f0 = (int)(i & (F - 1));
    uint4 v = *(uint4*)(x + i);
    float y0 = bf_lo(v.x), y1 = bf_hi(v.x), y2 = bf_lo(v.y), y3 = bf_hi(v.y);
    float y4 = bf_lo(v.z), y5 = bf_hi(v.z), y6 = bf_lo(v.w), y7 = bf_hi(v.w);
    float t;
    t = y0 * ac[f0 + 0] + ac[F + f0 + 0]; y0 = t > 0.f ? t : 0.f;
    t = y1 * ac[f0 + 1] + ac[F + f0 + 1]; y1 = t > 0.f ? t : 0.f;
    t = y2 * ac[f0 + 2] + ac[F + f0 + 2]; y2 = t > 0.f ? t : 0.f;
    t = y3 * ac[f0 + 3] + ac[F + f0 + 3]; y3 = t > 0.f ? t : 0.f;
    t = y4 * ac[f0 + 4] + ac[F + f0 + 4]; y4 = t > 0.f ? t : 0.f;
    t = y5 * ac[f0 + 5] + ac[F + f0 + 5]; y5 = t > 0.f ? t : 0.f;
    t = y6 * ac[f0 + 6] + ac[F + f0 + 6]; y6 = t > 0.f ? t : 0.f;
    t = y7 * ac[f0 + 7] + ac[F + f0 + 7]; y7 = t > 0.f ? t : 0.f;
    uint4 o;
    o.x = pack2(y0, y1); o.y = pack2(y2, y3);
    o.z = pack2(y4, y5); o.w = pack2(y6, y7);
    *(uint4*)(x + i) = o;
}

// ---------------------------------------------------------------------------
// fused mean-pool + linear head + sigmoid (bf16 input)
__global__ void k_pool_bf(const u16* __restrict__ h, const int* __restrict__ gstart,
                          const float* __restrict__ Wl, const float* __restrict__ bl,
                          float* __restrict__ out) {
    const int g = blockIdx.x;
    const int s = gstart[g], e = gstart[g + 1];
    const int f = threadIdx.x & 31, c = threadIdx.x >> 5;
    float acc = 0.0f;
    for (int r = s + c; r < e; r += 8) acc += bf_lo((u32)h[(size_t)r * 32 + f]);
    __shared__ float red[8][32];
    red[c][f] = acc;
    __syncthreads();
    if (threadIdx.x < 32) {
        float t = 0.0f;
        #pragma unroll
        for (int i = 0; i < 8; ++i) t += red[i][f];
        float cntf = (float)(e - s);
        cntf = cntf > 1.0f ? cntf : 1.0f;
        float p = (t / cntf) * Wl[f];
        #pragma unroll
        for (int off = 16; off > 0; off >>= 1) p += __shfl_down(p, off, 32);
        if (f == 0) out[g] = 1.0f / (1.0f + expf(-(p + bl[0])));
    }
}

// ---------------------------------------------------------------------------
extern "C" void kernel_launch(void* const* d_in, const int* in_sizes, int n_in,
                              void* d_out, int out_size, void* d_ws, size_t ws_size,
                              hipStream_t stream) {
    const float* x     = (const float*)d_in[0];
    const int*   ei    = (const int*)d_in[1];
    const float* ew    = (const float*)d_in[2];
    const int*   batch = (const int*)d_in[3];
    const float* W1 = (const float*)d_in[4];
    const float* g1 = (const float*)d_in[6];
    const float* be1 = (const float*)d_in[7];
    const float* W2 = (const float*)d_in[8];
    const float* g2 = (const float*)d_in[10];
    const float* be2 = (const float*)d_in[11];
    const float* W3 = (const float*)d_in[12];
    const float* g3 = (const float*)d_in[14];
    const float* be3 = (const float*)d_in[15];
    const float* W4 = (const float*)d_in[16];
    const float* g4 = (const float*)d_in[18];
    const float* be4 = (const float*)d_in[19];
    const float* Wl = (const float*)d_in[20];
    const float* bl = (const float*)d_in[21];
    float* out = (float*)d_out;

    char* ws = (char*)d_ws;
    size_t off = 0;
    auto alloc = [&](size_t bytes) -> void* {
        void* p = ws + off;
        off += (bytes + 255) & ~(size_t)255;
        return p;
    };
    // zeroed region first (one memset)
    float* deg   = (float*)alloc((size_t)NN * 4);
    int*   cnt   = (int*)  alloc((size_t)NN * 4);
    const size_t zero_bytes = off;
    // non-zeroed
    int*   flag   = (int*)  alloc(256);
    float* ac     = (float*)alloc(512 * 4);
    float* P      = (float*)alloc((size_t)NBLK_ST * 512 * 4);   // BN partials
    int*   gstart = (int*)  alloc((NG + 1) * 4);
    int*   rowptr = (int*)  alloc((size_t)(NN + 1) * 4);
    int*   cursor = (int*)  alloc((size_t)NN * 4);
    float* dis    = (float*)alloc((size_t)NN * 4);
    int*   col    = (int*)  alloc((size_t)NT * 4);
    float* val    = (float*)alloc((size_t)NT * 4);
    u16*   xb     = (u16*)  alloc((size_t)NNP * 128 * 2);
    u16*   wt1    = (u16*)  alloc((size_t)256 * 128 * 2);
    u16*   wt2    = (u16*)  alloc((size_t)128 * 256 * 2);
    u16*   wt3    = (u16*)  alloc((size_t)64 * 128 * 2);
    u16*   wt4    = (u16*)  alloc((size_t)32 * 64 * 2);
    u16*   bufA   = (u16*)  alloc((size_t)NNP * 256 * 2);
    u16*   bufB   = (u16*)  alloc((size_t)NNP * 256 * 2);

    hipMemsetAsync(d_ws, 0, zero_bytes, stream);

    const int egrid = (NT + 255) / 256;
    const int mg = (NN + 127) / 128;     // GEMM grid.x

    k_detect<<<1, 64, 0, stream>>>(ei, flag);
    k_deg_count<<<egrid, 256, 0, stream>>>(ei, ew, flag, deg, cnt);
    k_scan<<<1, 1024, 0, stream>>>(cnt, rowptr, cursor);
    k_dis<<<(NN + 255) / 256, 256, 0, stream>>>(deg, dis);
    k_csr<<<egrid, 256, 0, stream>>>(ei, ew, flag, dis, cursor, col, val);
    k_bounds<<<1, 128, 0, stream>>>(batch, flag, gstart);

    k_cvt<<<(int)(((size_t)NN * 128 / 8 + 255) / 256), 256, 0, stream>>>(x, xb);
    k_wt<<<(128 * 256 + 255) / 256, 256, 0, stream>>>(W1, wt1, 128, 256);
    k_wt<<<(256 * 128 + 255) / 256, 256, 0, stream>>>(W2, wt2, 256, 128);
    k_wt<<<(128 * 64 + 255) / 256, 256, 0, stream>>>(W3, wt3, 128, 64);
    k_wt<<<(64 * 32 + 255) / 256, 256, 0, stream>>>(W4, wt4, 64, 32);

    // ---- layer 1: aggregate(128) -> GEMM 128->256 -> BN+ReLU
    k_spmm_bf<128><<<(NN + 15) / 16, 256, 0, stream>>>(rowptr, col, val, xb, bufA);
    k_gemm_bf<128, 64><<<dim3(mg, 4), 256, 0, stream>>>(bufA, wt1, bufB, NN, 256);
    k_bn_stats2<256><<<NBLK_ST, 256, 0, stream>>>(bufB, P);
    k_bn_red<256><<<1, 256, 0, stream>>>(P, g1, be1, ac);
    k_bn_apply_bf<256><<<(int)(((size_t)NN * 256 / 8 + 255) / 256), 256, 0, stream>>>(bufB, ac);

    // ---- layer 2: GEMM 256->128 -> aggregate(128) -> BN+ReLU
    k_gemm_bf<256, 64><<<dim3(mg, 2), 256, 0, stream>>>(bufB, wt2, bufA, NN, 128);
    k_spmm_bf<128><<<(NN + 15) / 16, 256, 0, stream>>>(rowptr, col, val, bufA, bufB);
    k_bn_stats2<128><<<NBLK_ST, 256, 0, stream>>>(bufB, P);
    k_bn_red<128><<<1, 128, 0, stream>>>(P, g2, be2, ac);
    k_bn_apply_bf<128><<<(int)(((size_t)NN * 128 / 8 + 255) / 256), 256, 0, stream>>>(bufB, ac);

    // ---- layer 3: GEMM 128->64 -> aggregate(64) -> BN+ReLU
    k_gemm_bf<128, 64><<<dim3(mg, 1), 256, 0, stream>>>(bufB, wt3, bufA, NN, 64);
    k_spmm_bf<64><<<(NN + 31) / 32, 256, 0, stream>>>(rowptr, col, val, bufA, bufB);
    k_bn_stats2<64><<<NBLK_ST, 256, 0, stream>>>(bufB, P);
    k_bn_red<64><<<1, 64, 0, stream>>>(P, g3, be3, ac);
    k_bn_apply_bf<64><<<(int)(((size_t)NN * 64 / 8 + 255) / 256), 256, 0, stream>>>(bufB, ac);

    // ---- layer 4: GEMM 64->32 -> aggregate(32) -> BN+ReLU
    k_gemm_bf<64, 32><<<dim3(mg, 1), 256, 0, stream>>>(bufB, wt4, bufA, NN, 32);
    k_spmm_bf<32><<<(NN + 63) / 64, 256, 0, stream>>>(rowptr, col, val, bufA, bufB);
    k_bn_stats2<32><<<NBLK_ST, 256, 0, stream>>>(bufB, P);
    k_bn_red<32><<<1, 64, 0, stream>>>(P, g4, be4, ac);
    k_bn_apply_bf<32><<<(int)(((size_t)NN * 32 / 8 + 255) / 256), 256, 0, stream>>>(bufB, ac);

    // ---- fused pool + head
    k_pool_bf<<<NG, 256, 0, stream>>>(bufB, gstart, Wl, bl, out);
}

// Round 5
// 499.543 us; speedup vs baseline: 2.7527x; 1.0837x over previous
//
#include <hip/hip_runtime.h>
#include <cstdint>
#include <cstddef>

#define NN 50000            // nodes
#define NNP 50176           // padded rows (GEMM tile overreach stays in-bounds)
#define NE 800000           // edges (before self loops)
#define NT (NE + NN)        // edges incl self loops
#define NG 64               // graphs
#define BN_EPS 1e-5f
#define NBLK_ST 500         // BN-stats blocks
#define ROWS_ST 100         // rows per BN-stats block (500*100 = 50000)
#define DEG_SCALE 65536.0f  // fixed-point scale for packed weighted degree

typedef unsigned int u32;
typedef unsigned short u16;
typedef unsigned long long u64;

using short8 = __attribute__((ext_vector_type(8))) short;  // 8 bf16 (4 VGPRs)
using f32x4  = __attribute__((ext_vector_type(4))) float;

__device__ __forceinline__ float bf_lo(u32 u) { return __builtin_bit_cast(float, u << 16); }
__device__ __forceinline__ float bf_hi(u32 u) { return __builtin_bit_cast(float, u & 0xffff0000u); }
__device__ __forceinline__ u32 f2bf(float f) {           // RNE float->bf16
    u32 u = __builtin_bit_cast(u32, f);
    return (u + 0x7fffu + ((u >> 16) & 1u)) >> 16;
}
__device__ __forceinline__ u32 pack2(float a, float b) { return f2bf(a) | (f2bf(b) << 16); }

__device__ __forceinline__ void gload16(const void* g, void* lds) {
    __builtin_amdgcn_global_load_lds((const __attribute__((address_space(1))) u32*)g,
                                     (__attribute__((address_space(3))) u32*)lds, 16, 0, 0);
}

// ---------------------------------------------------------------------------
// int64-vs-int32 detection for edge_index / batch
__global__ void k_detect(const int* __restrict__ ei, int* __restrict__ flag) {
    if (blockIdx.x == 0 && threadIdx.x == 0) {
        int is64 = (ei[1] == 0 && ei[3] == 0 && ei[5] == 0 && ei[7] == 0) ? 1 : 0;
        *flag = is64;
    }
}

__device__ __forceinline__ int ld_idx(const int* __restrict__ p, long i, int is64) {
    return is64 ? p[2 * i] : p[i];
}

// ---------------------------------------------------------------------------
// packed weighted-degree + count: ONE u64 atomic per edge.
// bits [40,64): edge count; bits [0,40): sum of w * 2^16 (max 5.6e10 < 2^40)
__global__ void k_deg_count(const int* __restrict__ ei, const float* __restrict__ ew,
                            const int* __restrict__ flag, u64* __restrict__ cnt64) {
    const int is64 = *flag;
    int i = blockIdx.x * 256 + threadIdx.x;
    const int stride = gridDim.x * 256;
    for (; i < NT; i += stride) {
        int d; float w;
        if (i < NE) { d = ld_idx(ei, (long)NE + i, is64); w = ew[i]; }
        else        { d = i - NE;                          w = 1.0f;  }
        const u64 v = ((u64)1 << 40) | (u64)__float2uint_rn(w * DEG_SCALE);
        atomicAdd(&cnt64[d], v);
    }
}

// exclusive prefix sum of packed counts -> rowptr/cursor; also dis = deg^-1/2.
__global__ void k_scan(const u64* __restrict__ cnt64, int* __restrict__ rowptr,
                       int* __restrict__ cursor, float* __restrict__ dis) {
    __shared__ int warp_excl[16];
    __shared__ int s_base;
    __shared__ int s_chunk_total;
    const int tid  = threadIdx.x;
    const int lane = tid & 63;
    const int wid  = tid >> 6;
    if (tid == 0) s_base = 0;
    __syncthreads();
    for (int start = 0; start < NN; start += 1024) {
        const int idx = start + tid;
        u64 packed = 0;
        if (idx < NN) packed = cnt64[idx];
        const int v = (int)(packed >> 40);
        if (idx < NN) {
            const float deg = (float)(packed & (((u64)1 << 40) - 1)) * (1.0f / DEG_SCALE);
            dis[idx] = deg > 0.0f ? rsqrtf(deg) : 0.0f;
        }
        int s = v;
        #pragma unroll
        for (int off = 1; off < 64; off <<= 1) {
            int t = __shfl_up(s, off, 64);
            if (lane >= off) s += t;
        }
        if (lane == 63) warp_excl[wid] = s;
        __syncthreads();
        if (tid == 0) {
            int acc = 0;
            #pragma unroll
            for (int w = 0; w < 16; ++w) { int t = warp_excl[w]; warp_excl[w] = acc; acc += t; }
        }
        __syncthreads();
        const int incl = s + warp_excl[wid];
        if (tid == 1023) s_chunk_total = incl;
        const int excl = incl - v;
        if (idx < NN) { const int r = s_base + excl; rowptr[idx] = r; cursor[idx] = r; }
        __syncthreads();
        if (tid == 0) s_base += s_chunk_total;
        __syncthreads();
    }
    if (tid == 0) rowptr[NN] = s_base;
}

// scatter edges into CSR (by dst): ONE packed 8B store per edge.
// lo 32 = src index, hi 32 = norm value bits (dis[src]*w*dis[dst])
__global__ void k_csr(const int* __restrict__ ei, const float* __restrict__ ew,
                      const int* __restrict__ flag, const float* __restrict__ dis,
                      int* __restrict__ cursor, u64* __restrict__ edges) {
    const int is64 = *flag;
    int i = blockIdx.x * 256 + threadIdx.x;
    const int stride = gridDim.x * 256;
    for (; i < NT; i += stride) {
        int s, d; float w;
        if (i < NE) { s = ld_idx(ei, i, is64); d = ld_idx(ei, (long)NE + i, is64); w = ew[i]; }
        else        { s = d = i - NE;          w = 1.0f;  }
        const int pos = atomicAdd(&cursor[d], 1);
        const float nv = dis[s] * w * dis[d];
        edges[pos] = (u64)(u32)s | ((u64)__builtin_bit_cast(u32, nv) << 32);
    }
}

__global__ void k_bounds(const int* __restrict__ batch, const int* __restrict__ flag,
                         int* __restrict__ gstart) {
    const int g = threadIdx.x;
    if (g > NG) return;
    const int is64 = *flag;
    int lo = 0, hi = NN;
    while (lo < hi) {
        const int mid = (lo + hi) >> 1;
        if (ld_idx(batch, mid, is64) < g) lo = mid + 1; else hi = mid;
    }
    gstart[g] = lo;
}

// ---------------------------------------------------------------------------
// conversions
__global__ void k_cvt(const float* __restrict__ x, u16* __restrict__ xb) {
    const size_t i = ((size_t)blockIdx.x * 256 + threadIdx.x) * 8;
    if (i >= (size_t)NN * 128) return;
    const float4 a = *(const float4*)(x + i);
    const float4 b = *(const float4*)(x + i + 4);
    uint4 o;
    o.x = pack2(a.x, a.y); o.y = pack2(a.z, a.w);
    o.z = pack2(b.x, b.y); o.w = pack2(b.z, b.w);
    *(uint4*)(xb + i) = o;
}

// W[K][N] fp32 -> Wt[N][K] bf16
__global__ void k_wt(const float* __restrict__ W, u16* __restrict__ Wt, int Kd, int Nd) {
    const int i = blockIdx.x * 256 + threadIdx.x;
    if (i >= Kd * Nd) return;
    const int k = i / Nd, n = i % Nd;
    Wt[(size_t)n * Kd + k] = (u16)f2bf(W[i]);
}

// ---------------------------------------------------------------------------
// SpMM bf16: out[v][f] = sum_e val[e] * x[col[e]][f]; 8 feats/lane, fp32 acc
template <int F>
__global__ void k_spmm_bf(const int* __restrict__ rowptr, const u64* __restrict__ edges,
                          const u16* __restrict__ x, u16* __restrict__ out) {
    constexpr int L = F / 8;
    constexpr int NPB = 256 / L;
    const int node = blockIdx.x * NPB + threadIdx.x / L;
    const int q = threadIdx.x % L;
    if (node >= NN) return;
    const int beg = rowptr[node], end = rowptr[node + 1];
    float a0 = 0, a1 = 0, a2 = 0, a3 = 0, a4 = 0, a5 = 0, a6 = 0, a7 = 0;
    for (int e = beg; e < end; ++e) {
        const u64 ev = edges[e];
        const int s = (int)(u32)ev;
        const float v = __builtin_bit_cast(float, (u32)(ev >> 32));
        const uint4 xv = *(const uint4*)(x + (size_t)s * F + q * 8);
        a0 += v * bf_lo(xv.x); a1 += v * bf_hi(xv.x);
        a2 += v * bf_lo(xv.y); a3 += v * bf_hi(xv.y);
        a4 += v * bf_lo(xv.z); a5 += v * bf_hi(xv.z);
        a6 += v * bf_lo(xv.w); a7 += v * bf_hi(xv.w);
    }
    uint4 o;
    o.x = pack2(a0, a1); o.y = pack2(a2, a3);
    o.z = pack2(a4, a5); o.w = pack2(a6, a7);
    *(uint4*)(out + (size_t)node * F + q * 8) = o;
}

// ---------------------------------------------------------------------------
// bf16 MFMA GEMM: C[M,N] = A[M,K] @ Wt[N,K]^T, all bf16, fp32 accum.
template <int K, int BN>
__global__ void k_gemm_bf(const u16* __restrict__ A, const u16* __restrict__ Wt,
                          u16* __restrict__ C, int M, int N) {
    constexpr int KS = K / 8;        // 16B slots per Wt row
    constexpr int CT = BN / 16;      // col tiles per block
    __shared__ alignas(16) u16 sW[BN * K];
    __shared__ alignas(16) u16 sA[2][128 * 32];
    const int tid  = threadIdx.x;
    const int lane = tid & 63;
    const int w    = tid >> 6;
    const int m0 = blockIdx.x * 128;
    const int n0 = blockIdx.y * BN;

    // stage whole Wt tile [BN][K]: phys slot s holds logical slot s^(row&7)
    #pragma unroll
    for (int i = 0; i < (BN * KS) / 256; ++i) {
        const int u = i * 256 + tid;
        const int r = u / KS;
        const int s = u % KS;
        const int ls = s ^ (r & 7);
        gload16(Wt + (size_t)(n0 + r) * K + ls * 8,
                (char*)sW + (i * 256 + w * 64) * 16);
    }
    // stage A chunk [128][32]: phys slot s holds logical slot s^((row>>1)&3)
    auto stageA = [&](int buf, int kt) {
        #pragma unroll
        for (int i = 0; i < 2; ++i) {
            const int u = i * 256 + tid;
            const int r = u >> 2;
            const int s = u & 3;
            const int ls = s ^ ((r >> 1) & 3);
            gload16(A + (size_t)(m0 + r) * K + kt + ls * 8,
                    (char*)&sA[buf][0] + (i * 256 + w * 64) * 16);
        }
    };
    stageA(0, 0);
    __syncthreads();

    f32x4 acc[2][CT] = {};
    const int rl  = lane & 15;
    const int k16 = lane >> 4;
    for (int ki = 0; ki < K / 32; ++ki) {
        if (ki + 1 < K / 32) stageA((ki + 1) & 1, (ki + 1) * 32);
        short8 af[2], bfr[CT];
        #pragma unroll
        for (int rt = 0; rt < 2; ++rt) {
            const int row = w * 32 + rt * 16 + rl;
            const int p = k16 ^ ((row >> 1) & 3);
            af[rt] = *(const short8*)((const char*)&sA[ki & 1][0] + row * 64 + p * 16);
        }
        #pragma unroll
        for (int ct = 0; ct < CT; ++ct) {
            const int c = ct * 16 + rl;
            const int p = (ki * 4 + k16) ^ (c & 7);
            bfr[ct] = *(const short8*)((const char*)sW + c * (K * 2) + p * 16);
        }
        #pragma unroll
        for (int rt = 0; rt < 2; ++rt)
            #pragma unroll
            for (int ct = 0; ct < CT; ++ct)
                acc[rt][ct] = __builtin_amdgcn_mfma_f32_16x16x32_bf16(af[rt], bfr[ct], acc[rt][ct], 0, 0, 0);
        __syncthreads();
    }

    #pragma unroll
    for (int rt = 0; rt < 2; ++rt) {
        #pragma unroll
        for (int r = 0; r < 4; ++r) {
            const int row = m0 + w * 32 + rt * 16 + k16 * 4 + r;
            if (row < M) {
                #pragma unroll
                for (int ct = 0; ct < CT; ++ct)
                    C[(size_t)row * N + n0 + ct * 16 + rl] = (u16)f2bf(acc[rt][ct][r]);
            }
        }
    }
}

// ---------------------------------------------------------------------------
// BN stats phase A: per-block partial sum/sumsq, vectorized, no global atomics.
template <int F>
__global__ void k_bn_stats2(const u16* __restrict__ x, float* __restrict__ P) {
    constexpr int LPR = F / 8;            // lanes per row
    constexpr int RPI = 256 / LPR;        // rows processed per iteration
    const int f8  = threadIdx.x % LPR;
    const int sub = threadIdx.x / LPR;
    const int r0 = blockIdx.x * ROWS_ST;
    int r1 = r0 + ROWS_ST; if (r1 > NN) r1 = NN;
    float s[8] = {}, ss[8] = {};
    for (int r = r0 + sub; r < r1; r += RPI) {
        const uint4 v = *(const uint4*)(x + (size_t)r * F + f8 * 8);
        float y;
        y = bf_lo(v.x); s[0] += y; ss[0] += y * y;
        y = bf_hi(v.x); s[1] += y; ss[1] += y * y;
        y = bf_lo(v.y); s[2] += y; ss[2] += y * y;
        y = bf_hi(v.y); s[3] += y; ss[3] += y * y;
        y = bf_lo(v.z); s[4] += y; ss[4] += y * y;
        y = bf_hi(v.z); s[5] += y; ss[5] += y * y;
        y = bf_lo(v.w); s[6] += y; ss[6] += y * y;
        y = bf_hi(v.w); s[7] += y; ss[7] += y * y;
    }
    __shared__ float ls[2 * F];
    for (int i = threadIdx.x; i < 2 * F; i += 256) ls[i] = 0.0f;
    __syncthreads();
    #pragma unroll
    for (int j = 0; j < 8; ++j) {
        atomicAdd(&ls[f8 * 8 + j], s[j]);
        atomicAdd(&ls[F + f8 * 8 + j], ss[j]);
    }
    __syncthreads();
    float* Pb = P + (size_t)blockIdx.x * (2 * F);
    for (int i = threadIdx.x; i < 2 * F; i += 256) Pb[i] = ls[i];
}

// BN stats phase B: reduce partials + produce fused affine coefficients.
template <int F>
__global__ void k_bn_red(const float* __restrict__ P, const float* __restrict__ g,
                         const float* __restrict__ be, float* __restrict__ ac) {
    const int f = threadIdx.x;
    if (f >= F) return;
    float s = 0.0f, ss = 0.0f;
    for (int b = 0; b < NBLK_ST; ++b) {
        s  += P[(size_t)b * (2 * F) + f];
        ss += P[(size_t)b * (2 * F) + F + f];
    }
    const float mu  = s * (1.0f / NN);
    const float var = ss * (1.0f / NN) - mu * mu;
    const float a = g[f] * rsqrtf(var + BN_EPS);
    ac[f]     = a;
    ac[F + f] = be[f] - mu * a;
}

template <int F>
__global__ void k_bn_apply_bf(u16* __restrict__ x, const float* __restrict__ ac) {
    const size_t i = ((size_t)blockIdx.x * 256 + threadIdx.x) * 8;
    if (i >= (size_t)NN * F) return;
    const int f0 = (int)(i & (F - 1));
    uint4 v = *(uint4*)(x + i);
    float y0 = bf_lo(v.x), y1 = bf_hi(v.x), y2 = bf_lo(v.y), y3 = bf_hi(v.y);
    float y4 = bf_lo(v.z), y5 = bf_hi(v.z), y6 = bf_lo(v.w), y7 = bf_hi(v.w);
    float t;
    t = y0 * ac[f0 + 0] + ac[F + f0 + 0]; y0 = t > 0.f ? t : 0.f;
    t = y1 * ac[f0 + 1] + ac[F + f0 + 1]; y1 = t > 0.f ? t : 0.f;
    t = y2 * ac[f0 + 2] + ac[F + f0 + 2]; y2 = t > 0.f ? t : 0.f;
    t = y3 * ac[f0 + 3] + ac[F + f0 + 3]; y3 = t > 0.f ? t : 0.f;
    t = y4 * ac[f0 + 4] + ac[F + f0 + 4]; y4 = t > 0.f ? t : 0.f;
    t = y5 * ac[f0 + 5] + ac[F + f0 + 5]; y5 = t > 0.f ? t : 0.f;
    t = y6 * ac[f0 + 6] + ac[F + f0 + 6]; y6 = t > 0.f ? t : 0.f;
    t = y7 * ac[f0 + 7] + ac[F + f0 + 7]; y7 = t > 0.f ? t : 0.f;
    uint4 o;
    o.x = pack2(y0, y1); o.y = pack2(y2, y3);
    o.z = pack2(y4, y5); o.w = pack2(y6, y7);
    *(uint4*)(x + i) = o;
}

// ---------------------------------------------------------------------------
// fused mean-pool + linear head + sigmoid (bf16 input)
__global__ void k_pool_bf(const u16* __restrict__ h, const int* __restrict__ gstart,
                          const float* __restrict__ Wl, const float* __restrict__ bl,
                          float* __restrict__ out) {
    const int g = blockIdx.x;
    const int s = gstart[g], e = gstart[g + 1];
    const int f = threadIdx.x & 31, c = threadIdx.x >> 5;
    float acc = 0.0f;
    for (int r = s + c; r < e; r += 8) acc += bf_lo((u32)h[(size_t)r * 32 + f]);
    __shared__ float red[8][32];
    red[c][f] = acc;
    __syncthreads();
    if (threadIdx.x < 32) {
        float t = 0.0f;
        #pragma unroll
        for (int i = 0; i < 8; ++i) t += red[i][f];
        float cntf = (float)(e - s);
        cntf = cntf > 1.0f ? cntf : 1.0f;
        float p = (t / cntf) * Wl[f];
        #pragma unroll
        for (int off = 16; off > 0; off >>= 1) p += __shfl_down(p, off, 32);
        if (f == 0) out[g] = 1.0f / (1.0f + expf(-(p + bl[0])));
    }
}

// ---------------------------------------------------------------------------
extern "C" void kernel_launch(void* const* d_in, const int* in_sizes, int n_in,
                              void* d_out, int out_size, void* d_ws, size_t ws_size,
                              hipStream_t stream) {
    const float* x     = (const float*)d_in[0];
    const int*   ei    = (const int*)d_in[1];
    const float* ew    = (const float*)d_in[2];
    const int*   batch = (const int*)d_in[3];
    const float* W1 = (const float*)d_in[4];
    const float* g1 = (const float*)d_in[6];
    const float* be1 = (const float*)d_in[7];
    const float* W2 = (const float*)d_in[8];
    const float* g2 = (const float*)d_in[10];
    const float* be2 = (const float*)d_in[11];
    const float* W3 = (const float*)d_in[12];
    const float* g3 = (const float*)d_in[14];
    const float* be3 = (const float*)d_in[15];
    const float* W4 = (const float*)d_in[16];
    const float* g4 = (const float*)d_in[18];
    const float* be4 = (const float*)d_in[19];
    const float* Wl = (const float*)d_in[20];
    const float* bl = (const float*)d_in[21];
    float* out = (float*)d_out;

    char* ws = (char*)d_ws;
    size_t off = 0;
    auto alloc = [&](size_t bytes) -> void* {
        void* p = ws + off;
        off += (bytes + 255) & ~(size_t)255;
        return p;
    };
    // zeroed region first (one memset)
    u64* cnt64 = (u64*)alloc((size_t)NN * 8);
    const size_t zero_bytes = off;
    // non-zeroed
    int*   flag   = (int*)  alloc(256);
    float* ac     = (float*)alloc(512 * 4);
    float* P      = (float*)alloc((size_t)NBLK_ST * 512 * 4);   // BN partials
    int*   gstart = (int*)  alloc((NG + 1) * 4);
    int*   rowptr = (int*)  alloc((size_t)(NN + 1) * 4);
    int*   cursor = (int*)  alloc((size_t)NN * 4);
    float* dis    = (float*)alloc((size_t)NN * 4);
    u64*   edges  = (u64*)  alloc((size_t)NT * 8);
    u16*   xb     = (u16*)  alloc((size_t)NNP * 128 * 2);
    u16*   wt1    = (u16*)  alloc((size_t)256 * 128 * 2);
    u16*   wt2    = (u16*)  alloc((size_t)128 * 256 * 2);
    u16*   wt3    = (u16*)  alloc((size_t)64 * 128 * 2);
    u16*   wt4    = (u16*)  alloc((size_t)32 * 64 * 2);
    u16*   bufA   = (u16*)  alloc((size_t)NNP * 256 * 2);
    u16*   bufB   = (u16*)  alloc((size_t)NNP * 256 * 2);

    hipMemsetAsync(d_ws, 0, zero_bytes, stream);

    const int egrid = (NT + 255) / 256;
    const int mg = (NN + 127) / 128;     // GEMM grid.x

    k_detect<<<1, 64, 0, stream>>>(ei, flag);
    k_deg_count<<<egrid, 256, 0, stream>>>(ei, ew, flag, cnt64);
    k_scan<<<1, 1024, 0, stream>>>(cnt64, rowptr, cursor, dis);
    k_csr<<<egrid, 256, 0, stream>>>(ei, ew, flag, dis, cursor, edges);
    k_bounds<<<1, 128, 0, stream>>>(batch, flag, gstart);

    k_cvt<<<(int)(((size_t)NN * 128 / 8 + 255) / 256), 256, 0, stream>>>(x, xb);
    k_wt<<<(128 * 256 + 255) / 256, 256, 0, stream>>>(W1, wt1, 128, 256);
    k_wt<<<(256 * 128 + 255) / 256, 256, 0, stream>>>(W2, wt2, 256, 128);
    k_wt<<<(128 * 64 + 255) / 256, 256, 0, stream>>>(W3, wt3, 128, 64);
    k_wt<<<(64 * 32 + 255) / 256, 256, 0, stream>>>(W4, wt4, 64, 32);

    // ---- layer 1: aggregate(128) -> GEMM 128->256 -> BN+ReLU
    k_spmm_bf<128><<<(NN + 15) / 16, 256, 0, stream>>>(rowptr, edges, xb, bufA);
    k_gemm_bf<128, 64><<<dim3(mg, 4), 256, 0, stream>>>(bufA, wt1, bufB, NN, 256);
    k_bn_stats2<256><<<NBLK_ST, 256, 0, stream>>>(bufB, P);
    k_bn_red<256><<<1, 256, 0, stream>>>(P, g1, be1, ac);
    k_bn_apply_bf<256><<<(int)(((size_t)NN * 256 / 8 + 255) / 256), 256, 0, stream>>>(bufB, ac);

    // ---- layer 2: GEMM 256->128 -> aggregate(128) -> BN+ReLU
    k_gemm_bf<256, 64><<<dim3(mg, 2), 256, 0, stream>>>(bufB, wt2, bufA, NN, 128);
    k_spmm_bf<128><<<(NN + 15) / 16, 256, 0, stream>>>(rowptr, edges, bufA, bufB);
    k_bn_stats2<128><<<NBLK_ST, 256, 0, stream>>>(bufB, P);
    k_bn_red<128><<<1, 128, 0, stream>>>(P, g2, be2, ac);
    k_bn_apply_bf<128><<<(int)(((size_t)NN * 128 / 8 + 255) / 256), 256, 0, stream>>>(bufB, ac);

    // ---- layer 3: GEMM 128->64 -> aggregate(64) -> BN+ReLU
    k_gemm_bf<128, 64><<<dim3(mg, 1), 256, 0, stream>>>(bufB, wt3, bufA, NN, 64);
    k_spmm_bf<64><<<(NN + 31) / 32, 256, 0, stream>>>(rowptr, edges, bufA, bufB);
    k_bn_stats2<64><<<NBLK_ST, 256, 0, stream>>>(bufB, P);
    k_bn_red<64><<<1, 64, 0, stream>>>(P, g3, be3, ac);
    k_bn_apply_bf<64><<<(int)(((size_t)NN * 64 / 8 + 255) / 256), 256, 0, stream>>>(bufB, ac);

    // ---- layer 4: GEMM 64->32 -> aggregate(32) -> BN+ReLU
    k_gemm_bf<64, 32><<<dim3(mg, 1), 256, 0, stream>>>(bufB, wt4, bufA, NN, 32);
    k_spmm_bf<32><<<(NN + 63) / 64, 256, 0, stream>>>(rowptr, edges, bufA, bufB);
    k_bn_stats2<32><<<NBLK_ST, 256, 0, stream>>>(bufB, P);
    k_bn_red<32><<<1, 64, 0, stream>>>(P, g4, be4, ac);
    k_bn_apply_bf<32><<<(int)(((size_t)NN * 32 / 8 + 255) / 256), 256, 0, stream>>>(bufB, ac);

    // ---- fused pool + head
    k_pool_bf<<<NG, 256, 0, stream>>>(bufB, gstart, Wl, bl, out);
}

// Round 6
// 416.981 us; speedup vs baseline: 3.2978x; 1.1980x over previous
//
#include <hip/hip_runtime.h>
#include <cstdint>
#include <cstddef>

#define NN 50000            // nodes
#define NNP 50176           // padded rows (GEMM tile overreach stays in-bounds)
#define NE 800000           // edges (before self loops)
#define NT (NE + NN)        // edges incl self loops
#define NG 64               // graphs
#define BN_EPS 1e-5f
#define NBLK_ST 125         // BN-stats blocks
#define ROWS_ST 400         // rows per BN-stats block (125*400 = 50000)
#define DEG_SCALE 65536.0f  // fixed-point scale for packed weighted degree
#define SCB 196             // scan blocks (196*256 = 50176 >= NN)

typedef unsigned int u32;
typedef unsigned short u16;
typedef unsigned long long u64;

using short8 = __attribute__((ext_vector_type(8))) short;  // 8 bf16 (4 VGPRs)
using f32x4  = __attribute__((ext_vector_type(4))) float;

__device__ __forceinline__ float bf_lo(u32 u) { return __builtin_bit_cast(float, u << 16); }
__device__ __forceinline__ float bf_hi(u32 u) { return __builtin_bit_cast(float, u & 0xffff0000u); }
__device__ __forceinline__ u32 f2bf(float f) {           // RNE float->bf16
    u32 u = __builtin_bit_cast(u32, f);
    return (u + 0x7fffu + ((u >> 16) & 1u)) >> 16;
}
__device__ __forceinline__ u32 pack2(float a, float b) { return f2bf(a) | (f2bf(b) << 16); }

__device__ __forceinline__ void gload16(const void* g, void* lds) {
    __builtin_amdgcn_global_load_lds((const __attribute__((address_space(1))) u32*)g,
                                     (__attribute__((address_space(3))) u32*)lds, 16, 0, 0);
}

__device__ __forceinline__ int ld_idx(const int* __restrict__ p, long i, int is64) {
    return is64 ? p[2 * i] : p[i];
}

// ---------------------------------------------------------------------------
// meta: int64-vs-int32 detect + graph bounds (batch sorted -> binary search)
__global__ void k_meta(const int* __restrict__ ei, const int* __restrict__ batch,
                       int* __restrict__ flag, int* __restrict__ gstart) {
    __shared__ int s_is64;
    if (threadIdx.x == 0) {
        int is64 = (ei[1] == 0 && ei[3] == 0 && ei[5] == 0 && ei[7] == 0) ? 1 : 0;
        *flag = is64;
        s_is64 = is64;
    }
    __syncthreads();
    const int g = threadIdx.x;
    if (g > NG) return;
    const int is64 = s_is64;
    int lo = 0, hi = NN;
    while (lo < hi) {
        const int mid = (lo + hi) >> 1;
        if (ld_idx(batch, mid, is64) < g) lo = mid + 1; else hi = mid;
    }
    gstart[g] = lo;
}

// ---------------------------------------------------------------------------
// packed weighted-degree + count: ONE u64 atomic per edge.
// bits [40,64): edge count; bits [0,40): sum of w * 2^16 (max 5.6e10 < 2^40)
__global__ void k_deg_count(const int* __restrict__ ei, const float* __restrict__ ew,
                            const int* __restrict__ flag, u64* __restrict__ cnt64) {
    const int is64 = *flag;
    int i = blockIdx.x * 256 + threadIdx.x;
    const int stride = gridDim.x * 256;
    for (; i < NT; i += stride) {
        int d; float w;
        if (i < NE) { d = ld_idx(ei, (long)NE + i, is64); w = ew[i]; }
        else        { d = i - NE;                          w = 1.0f;  }
        const u64 v = ((u64)1 << 40) | (u64)__float2uint_rn(w * DEG_SCALE);
        atomicAdd(&cnt64[d], v);
    }
}

// ---------------------------------------------------------------------------
// multi-block scan, phase A: per-block chunk sums + dis = deg^-1/2
__global__ void k_scan_a(const u64* __restrict__ cnt64, int* __restrict__ blocksum,
                         float* __restrict__ dis) {
    const int tid = threadIdx.x;
    const int idx = blockIdx.x * 256 + tid;
    u64 packed = 0;
    if (idx < NN) {
        packed = cnt64[idx];
        const float deg = (float)(packed & (((u64)1 << 40) - 1)) * (1.0f / DEG_SCALE);
        dis[idx] = deg > 0.0f ? rsqrtf(deg) : 0.0f;
    }
    int v = (int)(packed >> 40);
    #pragma unroll
    for (int off = 32; off > 0; off >>= 1) v += __shfl_down(v, off, 64);
    __shared__ int wsum[4];
    if ((tid & 63) == 0) wsum[tid >> 6] = v;
    __syncthreads();
    if (tid == 0) blocksum[blockIdx.x] = wsum[0] + wsum[1] + wsum[2] + wsum[3];
}

// phase B: exclusive scan of SCB block sums (single small block)
__global__ void k_scan_b(const int* __restrict__ blocksum, int* __restrict__ blockoff,
                         int* __restrict__ rowptr) {
    const int tid = threadIdx.x;     // 256 >= SCB
    const int lane = tid & 63;
    const int wid = tid >> 6;
    const int v = (tid < SCB) ? blocksum[tid] : 0;
    int s = v;
    #pragma unroll
    for (int off = 1; off < 64; off <<= 1) {
        int t = __shfl_up(s, off, 64);
        if (lane >= off) s += t;
    }
    __shared__ int we[4];
    if (lane == 63) we[wid] = s;
    __syncthreads();
    int base = 0;
    for (int w = 0; w < 4; ++w) { if (w < wid) base += we[w]; }
    const int excl = base + s - v;
    if (tid < SCB) blockoff[tid] = excl;
    if (tid == SCB - 1) rowptr[NN] = excl + v;
}

// phase C: block-local exclusive scan + block offset -> rowptr & cursor
__global__ void k_scan_c(const u64* __restrict__ cnt64, const int* __restrict__ blockoff,
                         int* __restrict__ rowptr, int* __restrict__ cursor) {
    const int tid = threadIdx.x;
    const int idx = blockIdx.x * 256 + tid;
    const int lane = tid & 63;
    const int wid = tid >> 6;
    const int v = (idx < NN) ? (int)(cnt64[idx] >> 40) : 0;
    int s = v;
    #pragma unroll
    for (int off = 1; off < 64; off <<= 1) {
        int t = __shfl_up(s, off, 64);
        if (lane >= off) s += t;
    }
    __shared__ int we[4];
    if (lane == 63) we[wid] = s;
    __syncthreads();
    int base = blockoff[blockIdx.x];
    for (int w = 0; w < 4; ++w) { if (w < wid) base += we[w]; }
    if (idx < NN) {
        const int r = base + s - v;
        rowptr[idx] = r;
        cursor[idx] = r;
    }
}

// scatter edges into CSR (by dst): ONE packed 8B store per edge.
// lo 32 = src index, hi 32 = norm value bits (dis[src]*w*dis[dst])
__global__ void k_csr(const int* __restrict__ ei, const float* __restrict__ ew,
                      const int* __restrict__ flag, const float* __restrict__ dis,
                      int* __restrict__ cursor, u64* __restrict__ edges) {
    const int is64 = *flag;
    int i = blockIdx.x * 256 + threadIdx.x;
    const int stride = gridDim.x * 256;
    for (; i < NT; i += stride) {
        int s, d; float w;
        if (i < NE) { s = ld_idx(ei, i, is64); d = ld_idx(ei, (long)NE + i, is64); w = ew[i]; }
        else        { s = d = i - NE;          w = 1.0f;  }
        const int pos = atomicAdd(&cursor[d], 1);
        const float nv = dis[s] * w * dis[d];
        edges[pos] = (u64)(u32)s | ((u64)__builtin_bit_cast(u32, nv) << 32);
    }
}

// ---------------------------------------------------------------------------
// conversions
__global__ void k_cvt(const float* __restrict__ x, u16* __restrict__ xb) {
    const size_t i = ((size_t)blockIdx.x * 256 + threadIdx.x) * 8;
    if (i >= (size_t)NN * 128) return;
    const float4 a = *(const float4*)(x + i);
    const float4 b = *(const float4*)(x + i + 4);
    uint4 o;
    o.x = pack2(a.x, a.y); o.y = pack2(a.z, a.w);
    o.z = pack2(b.x, b.y); o.w = pack2(b.z, b.w);
    *(uint4*)(xb + i) = o;
}

// all four W[K][N] fp32 -> Wt[N][K] bf16 in one launch
__global__ void k_wt_all(const float* __restrict__ W1, const float* __restrict__ W2,
                         const float* __restrict__ W3, const float* __restrict__ W4,
                         u16* __restrict__ wt1, u16* __restrict__ wt2,
                         u16* __restrict__ wt3, u16* __restrict__ wt4) {
    int i = blockIdx.x * 256 + threadIdx.x;
    const float* W; u16* Wt; int Kd, Nd;
    if (i < 32768)      { W = W1; Wt = wt1; Kd = 128; Nd = 256; }
    else if (i < 65536) { W = W2; Wt = wt2; Kd = 256; Nd = 128; i -= 32768; }
    else if (i < 73728) { W = W3; Wt = wt3; Kd = 128; Nd = 64;  i -= 65536; }
    else if (i < 75776) { W = W4; Wt = wt4; Kd = 64;  Nd = 32;  i -= 73728; }
    else return;
    const int k = i / Nd, n = i % Nd;
    Wt[(size_t)n * Kd + k] = (u16)f2bf(W[i]);
}

// ---------------------------------------------------------------------------
// SpMM bf16: out[v][f] = sum_e val[e] * x[col[e]][f]; 8 feats/lane, fp32 acc
template <int F>
__global__ void k_spmm_bf(const int* __restrict__ rowptr, const u64* __restrict__ edges,
                          const u16* __restrict__ x, u16* __restrict__ out) {
    constexpr int L = F / 8;
    constexpr int NPB = 256 / L;
    const int node = blockIdx.x * NPB + threadIdx.x / L;
    const int q = threadIdx.x % L;
    if (node >= NN) return;
    const int beg = rowptr[node], end = rowptr[node + 1];
    float a0 = 0, a1 = 0, a2 = 0, a3 = 0, a4 = 0, a5 = 0, a6 = 0, a7 = 0;
    for (int e = beg; e < end; ++e) {
        const u64 ev = edges[e];
        const int s = (int)(u32)ev;
        const float v = __builtin_bit_cast(float, (u32)(ev >> 32));
        const uint4 xv = *(const uint4*)(x + (size_t)s * F + q * 8);
        a0 += v * bf_lo(xv.x); a1 += v * bf_hi(xv.x);
        a2 += v * bf_lo(xv.y); a3 += v * bf_hi(xv.y);
        a4 += v * bf_lo(xv.z); a5 += v * bf_hi(xv.z);
        a6 += v * bf_lo(xv.w); a7 += v * bf_hi(xv.w);
    }
    uint4 o;
    o.x = pack2(a0, a1); o.y = pack2(a2, a3);
    o.z = pack2(a4, a5); o.w = pack2(a6, a7);
    *(uint4*)(out + (size_t)node * F + q * 8) = o;
}

// ---------------------------------------------------------------------------
// bf16 MFMA GEMM: C[M,N] = A[M,K] @ Wt[N,K]^T, all bf16, fp32 accum.
template <int K, int BN>
__global__ void k_gemm_bf(const u16* __restrict__ A, const u16* __restrict__ Wt,
                          u16* __restrict__ C, int M, int N) {
    constexpr int KS = K / 8;        // 16B slots per Wt row
    constexpr int CT = BN / 16;      // col tiles per block
    __shared__ alignas(16) u16 sW[BN * K];
    __shared__ alignas(16) u16 sA[2][128 * 32];
    const int tid  = threadIdx.x;
    const int lane = tid & 63;
    const int w    = tid >> 6;
    const int m0 = blockIdx.x * 128;
    const int n0 = blockIdx.y * BN;

    // stage whole Wt tile [BN][K]: phys slot s holds logical slot s^(row&7)
    #pragma unroll
    for (int i = 0; i < (BN * KS) / 256; ++i) {
        const int u = i * 256 + tid;
        const int r = u / KS;
        const int s = u % KS;
        const int ls = s ^ (r & 7);
        gload16(Wt + (size_t)(n0 + r) * K + ls * 8,
                (char*)sW + (i * 256 + w * 64) * 16);
    }
    // stage A chunk [128][32]: phys slot s holds logical slot s^((row>>1)&3)
    auto stageA = [&](int buf, int kt) {
        #pragma unroll
        for (int i = 0; i < 2; ++i) {
            const int u = i * 256 + tid;
            const int r = u >> 2;
            const int s = u & 3;
            const int ls = s ^ ((r >> 1) & 3);
            gload16(A + (size_t)(m0 + r) * K + kt + ls * 8,
                    (char*)&sA[buf][0] + (i * 256 + w * 64) * 16);
        }
    };
    stageA(0, 0);
    __syncthreads();

    f32x4 acc[2][CT] = {};
    const int rl  = lane & 15;
    const int k16 = lane >> 4;
    for (int ki = 0; ki < K / 32; ++ki) {
        if (ki + 1 < K / 32) stageA((ki + 1) & 1, (ki + 1) * 32);
        short8 af[2], bfr[CT];
        #pragma unroll
        for (int rt = 0; rt < 2; ++rt) {
            const int row = w * 32 + rt * 16 + rl;
            const int p = k16 ^ ((row >> 1) & 3);
            af[rt] = *(const short8*)((const char*)&sA[ki & 1][0] + row * 64 + p * 16);
        }
        #pragma unroll
        for (int ct = 0; ct < CT; ++ct) {
            const int c = ct * 16 + rl;
            const int p = (ki * 4 + k16) ^ (c & 7);
            bfr[ct] = *(const short8*)((const char*)sW + c * (K * 2) + p * 16);
        }
        #pragma unroll
        for (int rt = 0; rt < 2; ++rt)
            #pragma unroll
            for (int ct = 0; ct < CT; ++ct)
                acc[rt][ct] = __builtin_amdgcn_mfma_f32_16x16x32_bf16(af[rt], bfr[ct], acc[rt][ct], 0, 0, 0);
        __syncthreads();
    }

    #pragma unroll
    for (int rt = 0; rt < 2; ++rt) {
        #pragma unroll
        for (int r = 0; r < 4; ++r) {
            const int row = m0 + w * 32 + rt * 16 + k16 * 4 + r;
            if (row < M) {
                #pragma unroll
                for (int ct = 0; ct < CT; ++ct)
                    C[(size_t)row * N + n0 + ct * 16 + rl] = (u16)f2bf(acc[rt][ct][r]);
            }
        }
    }
}

// ---------------------------------------------------------------------------
// BN stats phase A: per-block partial sum/sumsq, vectorized, no global atomics.
template <int F>
__global__ void k_bn_stats2(const u16* __restrict__ x, float* __restrict__ P) {
    constexpr int LPR = F / 8;            // lanes per row
    constexpr int RPI = 256 / LPR;        // rows processed per iteration
    const int f8  = threadIdx.x % LPR;
    const int sub = threadIdx.x / LPR;
    const int r0 = blockIdx.x * ROWS_ST;
    int r1 = r0 + ROWS_ST; if (r1 > NN) r1 = NN;
    float s[8] = {}, ss[8] = {};
    for (int r = r0 + sub; r < r1; r += RPI) {
        const uint4 v = *(const uint4*)(x + (size_t)r * F + f8 * 8);
        float y;
        y = bf_lo(v.x); s[0] += y; ss[0] += y * y;
        y = bf_hi(v.x); s[1] += y; ss[1] += y * y;
        y = bf_lo(v.y); s[2] += y; ss[2] += y * y;
        y = bf_hi(v.y); s[3] += y; ss[3] += y * y;
        y = bf_lo(v.z); s[4] += y; ss[4] += y * y;
        y = bf_hi(v.z); s[5] += y; ss[5] += y * y;
        y = bf_lo(v.w); s[6] += y; ss[6] += y * y;
        y = bf_hi(v.w); s[7] += y; ss[7] += y * y;
    }
    __shared__ float ls[2 * F];
    for (int i = threadIdx.x; i < 2 * F; i += 256) ls[i] = 0.0f;
    __syncthreads();
    #pragma unroll
    for (int j = 0; j < 8; ++j) {
        atomicAdd(&ls[f8 * 8 + j], s[j]);
        atomicAdd(&ls[F + f8 * 8 + j], ss[j]);
    }
    __syncthreads();
    float* Pb = P + (size_t)blockIdx.x * (2 * F);
    for (int i = threadIdx.x; i < 2 * F; i += 256) Pb[i] = ls[i];
}

// BN stats phase B: reduce partials + produce fused affine coefficients.
template <int F>
__global__ void k_bn_red(const float* __restrict__ P, const float* __restrict__ g,
                         const float* __restrict__ be, float* __restrict__ ac) {
    const int f = threadIdx.x;
    if (f >= F) return;
    float s = 0.0f, ss = 0.0f;
    for (int b = 0; b < NBLK_ST; ++b) {
        s  += P[(size_t)b * (2 * F) + f];
        ss += P[(size_t)b * (2 * F) + F + f];
    }
    const float mu  = s * (1.0f / NN);
    const float var = ss * (1.0f / NN) - mu * mu;
    const float a = g[f] * rsqrtf(var + BN_EPS);
    ac[f]     = a;
    ac[F + f] = be[f] - mu * a;
}

template <int F>
__global__ void k_bn_apply_bf(u16* __restrict__ x, const float* __restrict__ ac) {
    const size_t i = ((size_t)blockIdx.x * 256 + threadIdx.x) * 8;
    if (i >= (size_t)NN * F) return;
    const int f0 = (int)(i & (F - 1));
    uint4 v = *(uint4*)(x + i);
    float y0 = bf_lo(v.x), y1 = bf_hi(v.x), y2 = bf_lo(v.y), y3 = bf_hi(v.y);
    float y4 = bf_lo(v.z), y5 = bf_hi(v.z), y6 = bf_lo(v.w), y7 = bf_hi(v.w);
    float t;
    t = y0 * ac[f0 + 0] + ac[F + f0 + 0]; y0 = t > 0.f ? t : 0.f;
    t = y1 * ac[f0 + 1] + ac[F + f0 + 1]; y1 = t > 0.f ? t : 0.f;
    t = y2 * ac[f0 + 2] + ac[F + f0 + 2]; y2 = t > 0.f ? t : 0.f;
    t = y3 * ac[f0 + 3] + ac[F + f0 + 3]; y3 = t > 0.f ? t : 0.f;
    t = y4 * ac[f0 + 4] + ac[F + f0 + 4]; y4 = t > 0.f ? t : 0.f;
    t = y5 * ac[f0 + 5] + ac[F + f0 + 5]; y5 = t > 0.f ? t : 0.f;
    t = y6 * ac[f0 + 6] + ac[F + f0 + 6]; y6 = t > 0.f ? t : 0.f;
    t = y7 * ac[f0 + 7] + ac[F + f0 + 7]; y7 = t > 0.f ? t : 0.f;
    uint4 o;
    o.x = pack2(y0, y1); o.y = pack2(y2, y3);
    o.z = pack2(y4, y5); o.w = pack2(y6, y7);
    *(uint4*)(x + i) = o;
}

// ---------------------------------------------------------------------------
// fused mean-pool + linear head + sigmoid (bf16 input)
__global__ void k_pool_bf(const u16* __restrict__ h, const int* __restrict__ gstart,
                          const float* __restrict__ Wl, const float* __restrict__ bl,
                          float* __restrict__ out) {
    const int g = blockIdx.x;
    const int s = gstart[g], e = gstart[g + 1];
    const int f = threadIdx.x & 31, c = threadIdx.x >> 5;
    float acc = 0.0f;
    for (int r = s + c; r < e; r += 8) acc += bf_lo((u32)h[(size_t)r * 32 + f]);
    __shared__ float red[8][32];
    red[c][f] = acc;
    __syncthreads();
    if (threadIdx.x < 32) {
        float t = 0.0f;
        #pragma unroll
        for (int i = 0; i < 8; ++i) t += red[i][f];
        float cntf = (float)(e - s);
        cntf = cntf > 1.0f ? cntf : 1.0f;
        float p = (t / cntf) * Wl[f];
        #pragma unroll
        for (int off = 16; off > 0; off >>= 1) p += __shfl_down(p, off, 32);
        if (f == 0) out[g] = 1.0f / (1.0f + expf(-(p + bl[0])));
    }
}

// ---------------------------------------------------------------------------
extern "C" void kernel_launch(void* const* d_in, const int* in_sizes, int n_in,
                              void* d_out, int out_size, void* d_ws, size_t ws_size,
                              hipStream_t stream) {
    const float* x     = (const float*)d_in[0];
    const int*   ei    = (const int*)d_in[1];
    const float* ew    = (const float*)d_in[2];
    const int*   batch = (const int*)d_in[3];
    const float* W1 = (const float*)d_in[4];
    const float* g1 = (const float*)d_in[6];
    const float* be1 = (const float*)d_in[7];
    const float* W2 = (const float*)d_in[8];
    const float* g2 = (const float*)d_in[10];
    const float* be2 = (const float*)d_in[11];
    const float* W3 = (const float*)d_in[12];
    const float* g3 = (const float*)d_in[14];
    const float* be3 = (const float*)d_in[15];
    const float* W4 = (const float*)d_in[16];
    const float* g4 = (const float*)d_in[18];
    const float* be4 = (const float*)d_in[19];
    const float* Wl = (const float*)d_in[20];
    const float* bl = (const float*)d_in[21];
    float* out = (float*)d_out;

    char* ws = (char*)d_ws;
    size_t off = 0;
    auto alloc = [&](size_t bytes) -> void* {
        void* p = ws + off;
        off += (bytes + 255) & ~(size_t)255;
        return p;
    };
    // zeroed region first (one memset)
    u64* cnt64 = (u64*)alloc((size_t)NN * 8);
    const size_t zero_bytes = off;
    // non-zeroed
    int*   flag   = (int*)  alloc(256);
    float* ac     = (float*)alloc(512 * 4);
    float* P      = (float*)alloc((size_t)NBLK_ST * 512 * 4);   // BN partials
    int*   gstart = (int*)  alloc((NG + 1) * 4);
    int*   rowptr = (int*)  alloc((size_t)(NN + 1) * 4);
    int*   cursor = (int*)  alloc((size_t)NN * 4);
    int*   bsum   = (int*)  alloc((size_t)SCB * 4);
    int*   boff   = (int*)  alloc((size_t)SCB * 4);
    float* dis    = (float*)alloc((size_t)NN * 4);
    u64*   edges  = (u64*)  alloc((size_t)NT * 8);
    u16*   xb     = (u16*)  alloc((size_t)NNP * 128 * 2);
    u16*   wt1    = (u16*)  alloc((size_t)256 * 128 * 2);
    u16*   wt2    = (u16*)  alloc((size_t)128 * 256 * 2);
    u16*   wt3    = (u16*)  alloc((size_t)64 * 128 * 2);
    u16*   wt4    = (u16*)  alloc((size_t)32 * 64 * 2);
    u16*   bufA   = (u16*)  alloc((size_t)NNP * 256 * 2);
    u16*   bufB   = (u16*)  alloc((size_t)NNP * 256 * 2);

    hipMemsetAsync(d_ws, 0, zero_bytes, stream);

    const int egrid = (NT + 255) / 256;
    const int mg = (NN + 127) / 128;     // GEMM grid.x

    k_meta<<<1, 128, 0, stream>>>(ei, batch, flag, gstart);
    k_deg_count<<<egrid, 256, 0, stream>>>(ei, ew, flag, cnt64);
    k_scan_a<<<SCB, 256, 0, stream>>>(cnt64, bsum, dis);
    k_scan_b<<<1, 256, 0, stream>>>(bsum, boff, rowptr);
    k_scan_c<<<SCB, 256, 0, stream>>>(cnt64, boff, rowptr, cursor);
    k_csr<<<egrid, 256, 0, stream>>>(ei, ew, flag, dis, cursor, edges);

    k_cvt<<<(int)(((size_t)NN * 128 / 8 + 255) / 256), 256, 0, stream>>>(x, xb);
    k_wt_all<<<(75776 + 255) / 256, 256, 0, stream>>>(W1, W2, W3, W4, wt1, wt2, wt3, wt4);

    // ---- layer 1: aggregate(128) -> GEMM 128->256 -> BN+ReLU
    k_spmm_bf<128><<<(NN + 15) / 16, 256, 0, stream>>>(rowptr, edges, xb, bufA);
    k_gemm_bf<128, 64><<<dim3(mg, 4), 256, 0, stream>>>(bufA, wt1, bufB, NN, 256);
    k_bn_stats2<256><<<NBLK_ST, 256, 0, stream>>>(bufB, P);
    k_bn_red<256><<<1, 256, 0, stream>>>(P, g1, be1, ac);
    k_bn_apply_bf<256><<<(int)(((size_t)NN * 256 / 8 + 255) / 256), 256, 0, stream>>>(bufB, ac);

    // ---- layer 2: GEMM 256->128 -> aggregate(128) -> BN+ReLU
    k_gemm_bf<256, 64><<<dim3(mg, 2), 256, 0, stream>>>(bufB, wt2, bufA, NN, 128);
    k_spmm_bf<128><<<(NN + 15) / 16, 256, 0, stream>>>(rowptr, edges, bufA, bufB);
    k_bn_stats2<128><<<NBLK_ST, 256, 0, stream>>>(bufB, P);
    k_bn_red<128><<<1, 128, 0, stream>>>(P, g2, be2, ac);
    k_bn_apply_bf<128><<<(int)(((size_t)NN * 128 / 8 + 255) / 256), 256, 0, stream>>>(bufB, ac);

    // ---- layer 3: GEMM 128->64 -> aggregate(64) -> BN+ReLU
    k_gemm_bf<128, 64><<<dim3(mg, 1), 256, 0, stream>>>(bufB, wt3, bufA, NN, 64);
    k_spmm_bf<64><<<(NN + 31) / 32, 256, 0, stream>>>(rowptr, edges, bufA, bufB);
    k_bn_stats2<64><<<NBLK_ST, 256, 0, stream>>>(bufB, P);
    k_bn_red<64><<<1, 64, 0, stream>>>(P, g3, be3, ac);
    k_bn_apply_bf<64><<<(int)(((size_t)NN * 64 / 8 + 255) / 256), 256, 0, stream>>>(bufB, ac);

    // ---- layer 4: GEMM 64->32 -> aggregate(32) -> BN+ReLU
    k_gemm_bf<64, 32><<<dim3(mg, 1), 256, 0, stream>>>(bufB, wt4, bufA, NN, 32);
    k_spmm_bf<32><<<(NN + 63) / 64, 256, 0, stream>>>(rowptr, edges, bufA, bufB);
    k_bn_stats2<32><<<NBLK_ST, 256, 0, stream>>>(bufB, P);
    k_bn_red<32><<<1, 64, 0, stream>>>(P, g4, be4, ac);
    k_bn_apply_bf<32><<<(int)(((size_t)NN * 32 / 8 + 255) / 256), 256, 0, stream>>>(bufB, ac);

    // ---- fused pool + head
    k_pool_bf<<<NG, 256, 0, stream>>>(bufB, gstart, Wl, bl, out);
}

// Round 7
// 416.644 us; speedup vs baseline: 3.3004x; 1.0008x over previous
//
#include <hip/hip_runtime.h>
#include <cstdint>
#include <cstddef>

#define NN 50000            // nodes
#define NNP 50176           // padded rows (GEMM tile overreach stays in-bounds)
#define NE 800000           // edges (before self loops)
#define NT (NE + NN)        // edges incl self loops
#define NG 64               // graphs
#define BN_EPS 1e-5f
#define NBLK_ST 125         // BN-stats blocks
#define ROWS_ST 400         // rows per BN-stats block (125*400 = 50000)
#define DEG_SCALE 65536.0f  // fixed-point scale for packed weighted degree
#define SCB 196             // scan blocks (196*256 = 50176 >= NN)

typedef unsigned int u32;
typedef unsigned short u16;
typedef unsigned long long u64;

using short8 = __attribute__((ext_vector_type(8))) short;  // 8 bf16 (4 VGPRs)
using f32x4  = __attribute__((ext_vector_type(4))) float;

__device__ __forceinline__ float bf_lo(u32 u) { return __builtin_bit_cast(float, u << 16); }
__device__ __forceinline__ float bf_hi(u32 u) { return __builtin_bit_cast(float, u & 0xffff0000u); }
__device__ __forceinline__ u32 f2bf(float f) {           // RNE float->bf16
    u32 u = __builtin_bit_cast(u32, f);
    return (u + 0x7fffu + ((u >> 16) & 1u)) >> 16;
}
__device__ __forceinline__ u32 pack2(float a, float b) { return f2bf(a) | (f2bf(b) << 16); }

__device__ __forceinline__ void gload16(const void* g, void* lds) {
    __builtin_amdgcn_global_load_lds((const __attribute__((address_space(1))) u32*)g,
                                     (__attribute__((address_space(3))) u32*)lds, 16, 0, 0);
}

__device__ __forceinline__ int ld_idx(const int* __restrict__ p, long i, int is64) {
    return is64 ? p[2 * i] : p[i];
}

// ---------------------------------------------------------------------------
// meta: int64-vs-int32 detect + graph bounds (batch sorted -> binary search)
__global__ void k_meta(const int* __restrict__ ei, const int* __restrict__ batch,
                       int* __restrict__ flag, int* __restrict__ gstart) {
    __shared__ int s_is64;
    if (threadIdx.x == 0) {
        int is64 = (ei[1] == 0 && ei[3] == 0 && ei[5] == 0 && ei[7] == 0) ? 1 : 0;
        *flag = is64;
        s_is64 = is64;
    }
    __syncthreads();
    const int g = threadIdx.x;
    if (g > NG) return;
    const int is64 = s_is64;
    int lo = 0, hi = NN;
    while (lo < hi) {
        const int mid = (lo + hi) >> 1;
        if (ld_idx(batch, mid, is64) < g) lo = mid + 1; else hi = mid;
    }
    gstart[g] = lo;
}

// ---------------------------------------------------------------------------
// packed weighted-degree + count: ONE u64 atomic per edge.
// bits [40,64): edge count; bits [0,40): sum of w * 2^16 (max 5.6e10 < 2^40)
__global__ void k_deg_count(const int* __restrict__ ei, const float* __restrict__ ew,
                            const int* __restrict__ flag, u64* __restrict__ cnt64) {
    const int is64 = *flag;
    int i = blockIdx.x * 256 + threadIdx.x;
    const int stride = gridDim.x * 256;
    for (; i < NT; i += stride) {
        int d; float w;
        if (i < NE) { d = ld_idx(ei, (long)NE + i, is64); w = ew[i]; }
        else        { d = i - NE;                          w = 1.0f;  }
        const u64 v = ((u64)1 << 40) | (u64)__float2uint_rn(w * DEG_SCALE);
        atomicAdd(&cnt64[d], v);
    }
}

// ---------------------------------------------------------------------------
// multi-block scan, phase A: per-block chunk sums + dis = deg^-1/2
__global__ void k_scan_a(const u64* __restrict__ cnt64, int* __restrict__ blocksum,
                         float* __restrict__ dis) {
    const int tid = threadIdx.x;
    const int idx = blockIdx.x * 256 + tid;
    u64 packed = 0;
    if (idx < NN) {
        packed = cnt64[idx];
        const float deg = (float)(packed & (((u64)1 << 40) - 1)) * (1.0f / DEG_SCALE);
        dis[idx] = deg > 0.0f ? rsqrtf(deg) : 0.0f;
    }
    int v = (int)(packed >> 40);
    #pragma unroll
    for (int off = 32; off > 0; off >>= 1) v += __shfl_down(v, off, 64);
    __shared__ int wsum[4];
    if ((tid & 63) == 0) wsum[tid >> 6] = v;
    __syncthreads();
    if (tid == 0) blocksum[blockIdx.x] = wsum[0] + wsum[1] + wsum[2] + wsum[3];
}

// phase B: exclusive scan of SCB block sums (single small block)
__global__ void k_scan_b(const int* __restrict__ blocksum, int* __restrict__ blockoff,
                         int* __restrict__ rowptr) {
    const int tid = threadIdx.x;     // 256 >= SCB
    const int lane = tid & 63;
    const int wid = tid >> 6;
    const int v = (tid < SCB) ? blocksum[tid] : 0;
    int s = v;
    #pragma unroll
    for (int off = 1; off < 64; off <<= 1) {
        int t = __shfl_up(s, off, 64);
        if (lane >= off) s += t;
    }
    __shared__ int we[4];
    if (lane == 63) we[wid] = s;
    __syncthreads();
    int base = 0;
    for (int w = 0; w < 4; ++w) { if (w < wid) base += we[w]; }
    const int excl = base + s - v;
    if (tid < SCB) blockoff[tid] = excl;
    if (tid == SCB - 1) rowptr[NN] = excl + v;
}

// phase C: block-local exclusive scan + block offset -> rowptr & cursor
__global__ void k_scan_c(const u64* __restrict__ cnt64, const int* __restrict__ blockoff,
                         int* __restrict__ rowptr, int* __restrict__ cursor) {
    const int tid = threadIdx.x;
    const int idx = blockIdx.x * 256 + tid;
    const int lane = tid & 63;
    const int wid = tid >> 6;
    const int v = (idx < NN) ? (int)(cnt64[idx] >> 40) : 0;
    int s = v;
    #pragma unroll
    for (int off = 1; off < 64; off <<= 1) {
        int t = __shfl_up(s, off, 64);
        if (lane >= off) s += t;
    }
    __shared__ int we[4];
    if (lane == 63) we[wid] = s;
    __syncthreads();
    int base = blockoff[blockIdx.x];
    for (int w = 0; w < 4; ++w) { if (w < wid) base += we[w]; }
    if (idx < NN) {
        const int r = base + s - v;
        rowptr[idx] = r;
        cursor[idx] = r;
    }
}

// scatter edges into CSR (by dst): ONE packed 8B store per edge.
// lo 32 = src index, hi 32 = norm value bits (dis[src]*w*dis[dst])
__global__ void k_csr(const int* __restrict__ ei, const float* __restrict__ ew,
                      const int* __restrict__ flag, const float* __restrict__ dis,
                      int* __restrict__ cursor, u64* __restrict__ edges) {
    const int is64 = *flag;
    int i = blockIdx.x * 256 + threadIdx.x;
    const int stride = gridDim.x * 256;
    for (; i < NT; i += stride) {
        int s, d; float w;
        if (i < NE) { s = ld_idx(ei, i, is64); d = ld_idx(ei, (long)NE + i, is64); w = ew[i]; }
        else        { s = d = i - NE;          w = 1.0f;  }
        const int pos = atomicAdd(&cursor[d], 1);
        const float nv = dis[s] * w * dis[d];
        edges[pos] = (u64)(u32)s | ((u64)__builtin_bit_cast(u32, nv) << 32);
    }
}

// ---------------------------------------------------------------------------
// conversions
__global__ void k_cvt(const float* __restrict__ x, u16* __restrict__ xb) {
    const size_t i = ((size_t)blockIdx.x * 256 + threadIdx.x) * 8;
    if (i >= (size_t)NN * 128) return;
    const float4 a = *(const float4*)(x + i);
    const float4 b = *(const float4*)(x + i + 4);
    uint4 o;
    o.x = pack2(a.x, a.y); o.y = pack2(a.z, a.w);
    o.z = pack2(b.x, b.y); o.w = pack2(b.z, b.w);
    *(uint4*)(xb + i) = o;
}

// all four W[K][N] fp32 -> Wt[N][K] bf16 in one launch
__global__ void k_wt_all(const float* __restrict__ W1, const float* __restrict__ W2,
                         const float* __restrict__ W3, const float* __restrict__ W4,
                         u16* __restrict__ wt1, u16* __restrict__ wt2,
                         u16* __restrict__ wt3, u16* __restrict__ wt4) {
    int i = blockIdx.x * 256 + threadIdx.x;
    const float* W; u16* Wt; int Kd, Nd;
    if (i < 32768)      { W = W1; Wt = wt1; Kd = 128; Nd = 256; }
    else if (i < 65536) { W = W2; Wt = wt2; Kd = 256; Nd = 128; i -= 32768; }
    else if (i < 73728) { W = W3; Wt = wt3; Kd = 128; Nd = 64;  i -= 65536; }
    else if (i < 75776) { W = W4; Wt = wt4; Kd = 64;  Nd = 32;  i -= 73728; }
    else return;
    const int k = i / Nd, n = i % Nd;
    Wt[(size_t)n * Kd + k] = (u16)f2bf(W[i]);
}

// ---------------------------------------------------------------------------
// SpMM bf16: out[v][f] = sum_e val[e] * x[col[e]][f]; 8 feats/lane, fp32 acc
template <int F>
__global__ void k_spmm_bf(const int* __restrict__ rowptr, const u64* __restrict__ edges,
                          const u16* __restrict__ x, u16* __restrict__ out) {
    constexpr int L = F / 8;
    constexpr int NPB = 256 / L;
    const int node = blockIdx.x * NPB + threadIdx.x / L;
    const int q = threadIdx.x % L;
    if (node >= NN) return;
    const int beg = rowptr[node], end = rowptr[node + 1];
    float a0 = 0, a1 = 0, a2 = 0, a3 = 0, a4 = 0, a5 = 0, a6 = 0, a7 = 0;
    for (int e = beg; e < end; ++e) {
        const u64 ev = edges[e];
        const int s = (int)(u32)ev;
        const float v = __builtin_bit_cast(float, (u32)(ev >> 32));
        const uint4 xv = *(const uint4*)(x + (size_t)s * F + q * 8);
        a0 += v * bf_lo(xv.x); a1 += v * bf_hi(xv.x);
        a2 += v * bf_lo(xv.y); a3 += v * bf_hi(xv.y);
        a4 += v * bf_lo(xv.z); a5 += v * bf_hi(xv.z);
        a6 += v * bf_lo(xv.w); a7 += v * bf_hi(xv.w);
    }
    uint4 o;
    o.x = pack2(a0, a1); o.y = pack2(a2, a3);
    o.z = pack2(a4, a5); o.w = pack2(a6, a7);
    *(uint4*)(out + (size_t)node * F + q * 8) = o;
}

// ---------------------------------------------------------------------------
// bf16 MFMA GEMM: C[M,N] = A[M,K] @ Wt[N,K]^T, all bf16, fp32 accum.
template <int K, int BN>
__global__ void k_gemm_bf(const u16* __restrict__ A, const u16* __restrict__ Wt,
                          u16* __restrict__ C, int M, int N) {
    constexpr int KS = K / 8;        // 16B slots per Wt row
    constexpr int CT = BN / 16;      // col tiles per block
    __shared__ alignas(16) u16 sW[BN * K];
    __shared__ alignas(16) u16 sA[2][128 * 32];
    const int tid  = threadIdx.x;
    const int lane = tid & 63;
    const int w    = tid >> 6;
    const int m0 = blockIdx.x * 128;
    const int n0 = blockIdx.y * BN;

    // stage whole Wt tile [BN][K]: phys slot s holds logical slot s^(row&7)
    #pragma unroll
    for (int i = 0; i < (BN * KS) / 256; ++i) {
        const int u = i * 256 + tid;
        const int r = u / KS;
        const int s = u % KS;
        const int ls = s ^ (r & 7);
        gload16(Wt + (size_t)(n0 + r) * K + ls * 8,
                (char*)sW + (i * 256 + w * 64) * 16);
    }
    // stage A chunk [128][32]: phys slot s holds logical slot s^((row>>1)&3)
    auto stageA = [&](int buf, int kt) {
        #pragma unroll
        for (int i = 0; i < 2; ++i) {
            const int u = i * 256 + tid;
            const int r = u >> 2;
            const int s = u & 3;
            const int ls = s ^ ((r >> 1) & 3);
            gload16(A + (size_t)(m0 + r) * K + kt + ls * 8,
                    (char*)&sA[buf][0] + (i * 256 + w * 64) * 16);
        }
    };
    stageA(0, 0);
    __syncthreads();

    f32x4 acc[2][CT] = {};
    const int rl  = lane & 15;
    const int k16 = lane >> 4;
    for (int ki = 0; ki < K / 32; ++ki) {
        if (ki + 1 < K / 32) stageA((ki + 1) & 1, (ki + 1) * 32);
        short8 af[2], bfr[CT];
        #pragma unroll
        for (int rt = 0; rt < 2; ++rt) {
            const int row = w * 32 + rt * 16 + rl;
            const int p = k16 ^ ((row >> 1) & 3);
            af[rt] = *(const short8*)((const char*)&sA[ki & 1][0] + row * 64 + p * 16);
        }
        #pragma unroll
        for (int ct = 0; ct < CT; ++ct) {
            const int c = ct * 16 + rl;
            const int p = (ki * 4 + k16) ^ (c & 7);
            bfr[ct] = *(const short8*)((const char*)sW + c * (K * 2) + p * 16);
        }
        #pragma unroll
        for (int rt = 0; rt < 2; ++rt)
            #pragma unroll
            for (int ct = 0; ct < CT; ++ct)
                acc[rt][ct] = __builtin_amdgcn_mfma_f32_16x16x32_bf16(af[rt], bfr[ct], acc[rt][ct], 0, 0, 0);
        __syncthreads();
    }

    #pragma unroll
    for (int rt = 0; rt < 2; ++rt) {
        #pragma unroll
        for (int r = 0; r < 4; ++r) {
            const int row = m0 + w * 32 + rt * 16 + k16 * 4 + r;
            if (row < M) {
                #pragma unroll
                for (int ct = 0; ct < CT; ++ct)
                    C[(size_t)row * N + n0 + ct * 16 + rl] = (u16)f2bf(acc[rt][ct][r]);
            }
        }
    }
}

// ---------------------------------------------------------------------------
// BN stats phase A: per-block partial sum/sumsq, vectorized, no global atomics.
template <int F>
__global__ void k_bn_stats2(const u16* __restrict__ x, float* __restrict__ P) {
    constexpr int LPR = F / 8;            // lanes per row
    constexpr int RPI = 256 / LPR;        // rows processed per iteration
    const int f8  = threadIdx.x % LPR;
    const int sub = threadIdx.x / LPR;
    const int r0 = blockIdx.x * ROWS_ST;
    int r1 = r0 + ROWS_ST; if (r1 > NN) r1 = NN;
    float s[8] = {}, ss[8] = {};
    for (int r = r0 + sub; r < r1; r += RPI) {
        const uint4 v = *(const uint4*)(x + (size_t)r * F + f8 * 8);
        float y;
        y = bf_lo(v.x); s[0] += y; ss[0] += y * y;
        y = bf_hi(v.x); s[1] += y; ss[1] += y * y;
        y = bf_lo(v.y); s[2] += y; ss[2] += y * y;
        y = bf_hi(v.y); s[3] += y; ss[3] += y * y;
        y = bf_lo(v.z); s[4] += y; ss[4] += y * y;
        y = bf_hi(v.z); s[5] += y; ss[5] += y * y;
        y = bf_lo(v.w); s[6] += y; ss[6] += y * y;
        y = bf_hi(v.w); s[7] += y; ss[7] += y * y;
    }
    __shared__ float ls[2 * F];
    for (int i = threadIdx.x; i < 2 * F; i += 256) ls[i] = 0.0f;
    __syncthreads();
    #pragma unroll
    for (int j = 0; j < 8; ++j) {
        atomicAdd(&ls[f8 * 8 + j], s[j]);
        atomicAdd(&ls[F + f8 * 8 + j], ss[j]);
    }
    __syncthreads();
    float* Pb = P + (size_t)blockIdx.x * (2 * F);
    for (int i = threadIdx.x; i < 2 * F; i += 256) Pb[i] = ls[i];
}

// BN stats phase B: reduce partials + produce fused affine coefficients.
template <int F>
__global__ void k_bn_red(const float* __restrict__ P, const float* __restrict__ g,
                         const float* __restrict__ be, float* __restrict__ ac) {
    const int f = threadIdx.x;
    if (f >= F) return;
    float s = 0.0f, ss = 0.0f;
    for (int b = 0; b < NBLK_ST; ++b) {
        s  += P[(size_t)b * (2 * F) + f];
        ss += P[(size_t)b * (2 * F) + F + f];
    }
    const float mu  = s * (1.0f / NN);
    const float var = ss * (1.0f / NN) - mu * mu;
    const float a = g[f] * rsqrtf(var + BN_EPS);
    ac[f]     = a;
    ac[F + f] = be[f] - mu * a;
}

template <int F>
__global__ void k_bn_apply_bf(u16* __restrict__ x, const float* __restrict__ ac) {
    const size_t i = ((size_t)blockIdx.x * 256 + threadIdx.x) * 8;
    if (i >= (size_t)NN * F) return;
    const int f0 = (int)(i & (F - 1));
    uint4 v = *(uint4*)(x + i);
    float y0 = bf_lo(v.x), y1 = bf_hi(v.x), y2 = bf_lo(v.y), y3 = bf_hi(v.y);
    float y4 = bf_lo(v.z), y5 = bf_hi(v.z), y6 = bf_lo(v.w), y7 = bf_hi(v.w);
    float t;
    t = y0 * ac[f0 + 0] + ac[F + f0 + 0]; y0 = t > 0.f ? t : 0.f;
    t = y1 * ac[f0 + 1] + ac[F + f0 + 1]; y1 = t > 0.f ? t : 0.f;
    t = y2 * ac[f0 + 2] + ac[F + f0 + 2]; y2 = t > 0.f ? t : 0.f;
    t = y3 * ac[f0 + 3] + ac[F + f0 + 3]; y3 = t > 0.f ? t : 0.f;
    t = y4 * ac[f0 + 4] + ac[F + f0 + 4]; y4 = t > 0.f ? t : 0.f;
    t = y5 * ac[f0 + 5] + ac[F + f0 + 5]; y5 = t > 0.f ? t : 0.f;
    t = y6 * ac[f0 + 6] + ac[F + f0 + 6]; y6 = t > 0.f ? t : 0.f;
    t = y7 * ac[f0 + 7] + ac[F + f0 + 7]; y7 = t > 0.f ? t : 0.f;
    uint4 o;
    o.x = pack2(y0, y1); o.y = pack2(y2, y3);
    o.z = pack2(y4, y5); o.w = pack2(y6, y7);
    *(uint4*)(x + i) = o;
}

// ---------------------------------------------------------------------------
// fused mean-pool + linear head + sigmoid (bf16 input)
__global__ void k_pool_bf(const u16* __restrict__ h, const int* __restrict__ gstart,
                          const float* __restrict__ Wl, const float* __restrict__ bl,
                          float* __restrict__ out) {
    const int g = blockIdx.x;
    const int s = gstart[g], e = gstart[g + 1];
    const int f = threadIdx.x & 31, c = threadIdx.x >> 5;
    float acc = 0.0f;
    for (int r = s + c; r < e; r += 8) acc += bf_lo((u32)h[(size_t)r * 32 + f]);
    __shared__ float red[8][32];
    red[c][f] = acc;
    __syncthreads();
    if (threadIdx.x < 32) {
        float t = 0.0f;
        #pragma unroll
        for (int i = 0; i < 8; ++i) t += red[i][f];
        float cntf = (float)(e - s);
        cntf = cntf > 1.0f ? cntf : 1.0f;
        float p = (t / cntf) * Wl[f];
        #pragma unroll
        for (int off = 16; off > 0; off >>= 1) p += __shfl_down(p, off, 32);
        if (f == 0) out[g] = 1.0f / (1.0f + expf(-(p + bl[0])));
    }
}

// ---------------------------------------------------------------------------
extern "C" void kernel_launch(void* const* d_in, const int* in_sizes, int n_in,
                              void* d_out, int out_size, void* d_ws, size_t ws_size,
                              hipStream_t stream) {
    const float* x     = (const float*)d_in[0];
    const int*   ei    = (const int*)d_in[1];
    const float* ew    = (const float*)d_in[2];
    const int*   batch = (const int*)d_in[3];
    const float* W1 = (const float*)d_in[4];
    const float* g1 = (const float*)d_in[6];
    const float* be1 = (const float*)d_in[7];
    const float* W2 = (const float*)d_in[8];
    const float* g2 = (const float*)d_in[10];
    const float* be2 = (const float*)d_in[11];
    const float* W3 = (const float*)d_in[12];
    const float* g3 = (const float*)d_in[14];
    const float* be3 = (const float*)d_in[15];
    const float* W4 = (const float*)d_in[16];
    const float* g4 = (const float*)d_in[18];
    const float* be4 = (const float*)d_in[19];
    const float* Wl = (const float*)d_in[20];
    const float* bl = (const float*)d_in[21];
    float* out = (float*)d_out;

    char* ws = (char*)d_ws;
    size_t off = 0;
    auto alloc = [&](size_t bytes) -> void* {
        void* p = ws + off;
        off += (bytes + 255) & ~(size_t)255;
        return p;
    };
    // zeroed region first (one memset)
    u64* cnt64 = (u64*)alloc((size_t)NN * 8);
    const size_t zero_bytes = off;
    // non-zeroed
    int*   flag   = (int*)  alloc(256);
    float* ac     = (float*)alloc(512 * 4);
    float* P      = (float*)alloc((size_t)NBLK_ST * 512 * 4);   // BN partials
    int*   gstart = (int*)  alloc((NG + 1) * 4);
    int*   rowptr = (int*)  alloc((size_t)(NN + 1) * 4);
    int*   cursor = (int*)  alloc((size_t)NN * 4);
    int*   bsum   = (int*)  alloc((size_t)SCB * 4);
    int*   boff   = (int*)  alloc((size_t)SCB * 4);
    float* dis    = (float*)alloc((size_t)NN * 4);
    u64*   edges  = (u64*)  alloc((size_t)NT * 8);
    u16*   xb     = (u16*)  alloc((size_t)NNP * 128 * 2);
    u16*   wt1    = (u16*)  alloc((size_t)256 * 128 * 2);
    u16*   wt2    = (u16*)  alloc((size_t)128 * 256 * 2);
    u16*   wt3    = (u16*)  alloc((size_t)64 * 128 * 2);
    u16*   wt4    = (u16*)  alloc((size_t)32 * 64 * 2);
    u16*   bufA   = (u16*)  alloc((size_t)NNP * 256 * 2);
    u16*   bufB   = (u16*)  alloc((size_t)NNP * 256 * 2);

    hipMemsetAsync(d_ws, 0, zero_bytes, stream);

    const int egrid = (NT + 255) / 256;
    const int mg = (NN + 127) / 128;     // GEMM grid.x

    k_meta<<<1, 128, 0, stream>>>(ei, batch, flag, gstart);
    k_deg_count<<<egrid, 256, 0, stream>>>(ei, ew, flag, cnt64);
    k_scan_a<<<SCB, 256, 0, stream>>>(cnt64, bsum, dis);
    k_scan_b<<<1, 256, 0, stream>>>(bsum, boff, rowptr);
    k_scan_c<<<SCB, 256, 0, stream>>>(cnt64, boff, rowptr, cursor);
    k_csr<<<egrid, 256, 0, stream>>>(ei, ew, flag, dis, cursor, edges);

    k_cvt<<<(int)(((size_t)NN * 128 / 8 + 255) / 256), 256, 0, stream>>>(x, xb);
    k_wt_all<<<(75776 + 255) / 256, 256, 0, stream>>>(W1, W2, W3, W4, wt1, wt2, wt3, wt4);

    // ---- layer 1: aggregate(128) -> GEMM 128->256 -> BN+ReLU
    k_spmm_bf<128><<<(NN + 15) / 16, 256, 0, stream>>>(rowptr, edges, xb, bufA);
    k_gemm_bf<128, 64><<<dim3(mg, 4), 256, 0, stream>>>(bufA, wt1, bufB, NN, 256);
    k_bn_stats2<256><<<NBLK_ST, 256, 0, stream>>>(bufB, P);
    k_bn_red<256><<<1, 256, 0, stream>>>(P, g1, be1, ac);
    k_bn_apply_bf<256><<<(int)(((size_t)NN * 256 / 8 + 255) / 256), 256, 0, stream>>>(bufB, ac);

    // ---- layer 2: GEMM 256->128 -> aggregate(128) -> BN+ReLU
    k_gemm_bf<256, 64><<<dim3(mg, 2), 256, 0, stream>>>(bufB, wt2, bufA, NN, 128);
    k_spmm_bf<128><<<(NN + 15) / 16, 256, 0, stream>>>(rowptr, edges, bufA, bufB);
    k_bn_stats2<128><<<NBLK_ST, 256, 0, stream>>>(bufB, P);
    k_bn_red<128><<<1, 128, 0, stream>>>(P, g2, be2, ac);
    k_bn_apply_bf<128><<<(int)(((size_t)NN * 128 / 8 + 255) / 256), 256, 0, stream>>>(bufB, ac);

    // ---- layer 3: GEMM 128->64 -> aggregate(64) -> BN+ReLU
    k_gemm_bf<128, 64><<<dim3(mg, 1), 256, 0, stream>>>(bufB, wt3, bufA, NN, 64);
    k_spmm_bf<64><<<(NN + 31) / 32, 256, 0, stream>>>(rowptr, edges, bufA, bufB);
    k_bn_stats2<64><<<NBLK_ST, 256, 0, stream>>>(bufB, P);
    k_bn_red<64><<<1, 64, 0, stream>>>(P, g3, be3, ac);
    k_bn_apply_bf<64><<<(int)(((size_t)NN * 64 / 8 + 255) / 256), 256, 0, stream>>>(bufB, ac);

    // ---- layer 4: GEMM 64->32 -> aggregate(32) -> BN+ReLU
    k_gemm_bf<64, 32><<<dim3(mg, 1), 256, 0, stream>>>(bufB, wt4, bufA, NN, 32);
    k_spmm_bf<32><<<(NN + 63) / 64, 256, 0, stream>>>(rowptr, edges, bufA, bufB);
    k_bn_stats2<32><<<NBLK_ST, 256, 0, stream>>>(bufB, P);
    k_bn_red<32><<<1, 64, 0, stream>>>(P, g4, be4, ac);
    k_bn_apply_bf<32><<<(int)(((size_t)NN * 32 / 8 + 255) / 256), 256, 0, stream>>>(bufB, ac);

    // ---- fused pool + head
    k_pool_bf<<<NG, 256, 0, stream>>>(bufB, gstart, Wl, bl, out);
}